// Round 13
// baseline (1626.001 us; speedup 1.0000x reference)
//
#include <hip/hip_runtime.h>
#include <hip/hip_bf16.h>

typedef __bf16 bf16x8 __attribute__((ext_vector_type(8)));
typedef unsigned short u16x8 __attribute__((ext_vector_type(8)));
typedef float f32x4 __attribute__((ext_vector_type(4)));

#define DEV static __device__ __forceinline__

DEV unsigned short f2bf(float f){
  __hip_bfloat16 h = __float2bfloat16(f);
  return __builtin_bit_cast(unsigned short, h);
}
DEV float b2f(unsigned short u){
  return __bfloat162float(__builtin_bit_cast(__hip_bfloat16, u));
}
// gate math in exp2 domain: inputs pre-scaled by log2(e)
DEV float sig2(float xs){
  return __builtin_amdgcn_rcpf(1.0f + __builtin_amdgcn_exp2f(-xs));
}
DEV float tanh2s(float xs){
  return 1.0f - 2.0f*__builtin_amdgcn_rcpf(__builtin_amdgcn_exp2f(xs + xs) + 1.0f);
}
DEV float tanh_n(float x){
  return 1.0f - 2.0f*__builtin_amdgcn_rcpf(__builtin_amdgcn_exp2f(x * 2.885390082f) + 1.0f);
}
DEV void lds_barrier(){
  asm volatile("s_waitcnt lgkmcnt(0)\ns_barrier" ::: "memory");
}

// ---------------- utility kernels ----------------

__global__ void zero16(uint4* p, size_t n){
  size_t i = (size_t)blockIdx.x*blockDim.x + threadIdx.x;
  size_t st = (size_t)gridDim.x*blockDim.x;
  uint4 z = make_uint4(0u,0u,0u,0u);
  for (; i < n; i += st) p[i] = z;
}

// combined: zero hs conv-pad rows + STATE buffer (one dispatch per stage)
__global__ void zero_stage(unsigned short* hs, int NSEQ, int Qrows, int L, uint4* state){
  int i = blockIdx.x*256 + threadIdx.x;
  int padsN = NSEQ*6*384;
  if (i < padsN){
    int t = i/(6*384); int rem = i - t*(6*384);
    int r = rem/384, c = rem - r*384;
    int row = r < 3 ? r : L + r;
    hs[((size_t)t*Qrows + row)*384 + c] = 0;
  } else {
    int j = i - padsN;
    if (j < 196608) state[j] = make_uint4(0u,0u,0u,0u);
  }
}

// ---------------- fused prep: weight casts (log2e-scaled), bias combine, lwt build ----------------
__global__ void prep_all(
    const float* __restrict__ intra_wih, const float* __restrict__ intra_whh,
    const float* __restrict__ inter_wih, const float* __restrict__ inter_whh,
    const float* __restrict__ intra_bih, const float* __restrict__ intra_bhh,
    const float* __restrict__ inter_bih, const float* __restrict__ inter_bhh,
    const float* __restrict__ intra_lw,  const float* __restrict__ inter_lw,
    unsigned short* __restrict__ wib_a, unsigned short* __restrict__ whb_a,
    unsigned short* __restrict__ wib_e, unsigned short* __restrict__ whb_e,
    float* __restrict__ bias_a, float* __restrict__ bias_e,
    unsigned short* __restrict__ lwt_a, unsigned short* __restrict__ lwt_e)
{
  const float LOG2E = 1.4426950408889634f;
  int i = blockIdx.x*256 + threadIdx.x;
  if (i < 294912){
    int dn = i/192, k = i - dn*192;
    int c = k >> 2, kk = k & 3;
    wib_a[(size_t)dn*192 + kk*48 + c] = f2bf(intra_wih[i]*LOG2E);
  } else if (i < 589824){
    int j = i - 294912;
    whb_a[j] = f2bf(intra_whh[j]*LOG2E);
  } else if (i < 884736){
    int j = i - 589824;
    int dn = j/192, k = j - dn*192;
    int c = k >> 2, kk = k & 3;
    wib_e[(size_t)dn*192 + kk*48 + c] = f2bf(inter_wih[j]*LOG2E);
  } else if (i < 1179648){
    int j = i - 884736;
    whb_e[j] = f2bf(inter_whh[j]*LOG2E);
  } else if (i < 1181184){
    int j = i - 1179648;
    bias_a[j] = (intra_bih[j] + intra_bhh[j])*LOG2E;
  } else if (i < 1182720){
    int j = i - 1181184;
    bias_e[j] = (inter_bih[j] + inter_bhh[j])*LOG2E;
  } else if (i < 1256448){
    int j = i - 1182720;
    int m = j / 192; int rest = j - m*192; int c = rest >> 2; int k = rest & 3;
    int kap = k*384 + m;
    lwt_a[((size_t)(kap>>3)*48 + c)*8 + (kap&7)] = f2bf(intra_lw[j]);
  } else if (i < 1330176){
    int j = i - 1256448;
    int m = j / 192; int rest = j - m*192; int c = rest >> 2; int k = rest & 3;
    int kap = k*384 + m;
    lwt_e[((size_t)(kap>>3)*48 + c)*8 + (kap&7)] = f2bf(inter_lw[j]);
  }
}

// ---------------- LN over C + unfold -> bf16 unf[seq][l][kk*48+c] ----------------
__global__ __launch_bounds__(256) void ln_unf_intra(
    const float* __restrict__ in, const float* __restrict__ g,
    const float* __restrict__ be, unsigned short* __restrict__ unf)
{
  int bt = blockIdx.x; int b = bt >> 9, t = bt & 511;
  __shared__ float v[48][66];
  __shared__ float mu[65], rs[65];
  __shared__ float g_l[48], b_l[48];
  const float* base = in + (size_t)b*(48*512*65) + (size_t)t*65;
  for (int i = threadIdx.x; i < 48*65; i += 256){
    int c = i/65, q = i - c*65;
    v[c][q] = base[(size_t)c*(512*65) + q];
  }
  if (threadIdx.x < 48){ g_l[threadIdx.x] = g[threadIdx.x]; b_l[threadIdx.x] = be[threadIdx.x]; }
  __syncthreads();
  if (threadIdx.x < 65){
    int q = threadIdx.x; float s=0.f, s2=0.f;
    #pragma unroll
    for (int c = 0; c < 48; c++){ float x = v[c][q]; s += x; s2 += x*x; }
    float m = s*(1.0f/48.0f);
    mu[q] = m; rs[q] = rsqrtf(s2*(1.0f/48.0f) - m*m + 1e-5f);
  }
  __syncthreads();
  unsigned short* orow = unf + (size_t)(b*512 + t)*62*192;
  for (int idx = threadIdx.x; idx < 62*24; idx += 256){
    int l = idx/24, jg = idx - l*24;
    int kk = jg/6, c0 = (jg - kk*6)*8;
    int q = l + kk;
    ushort4 p0, p1;
    float mq = mu[q], rq = rs[q];
    p0.x = f2bf((v[c0+0][q]-mq)*rq*g_l[c0+0] + b_l[c0+0]);
    p0.y = f2bf((v[c0+1][q]-mq)*rq*g_l[c0+1] + b_l[c0+1]);
    p0.z = f2bf((v[c0+2][q]-mq)*rq*g_l[c0+2] + b_l[c0+2]);
    p0.w = f2bf((v[c0+3][q]-mq)*rq*g_l[c0+3] + b_l[c0+3]);
    p1.x = f2bf((v[c0+4][q]-mq)*rq*g_l[c0+4] + b_l[c0+4]);
    p1.y = f2bf((v[c0+5][q]-mq)*rq*g_l[c0+5] + b_l[c0+5]);
    p1.z = f2bf((v[c0+6][q]-mq)*rq*g_l[c0+6] + b_l[c0+6]);
    p1.w = f2bf((v[c0+7][q]-mq)*rq*g_l[c0+7] + b_l[c0+7]);
    *(ushort4*)(orow + (size_t)l*192 + kk*48 + c0) = p0;
    *(ushort4*)(orow + (size_t)l*192 + kk*48 + c0 + 4) = p1;
  }
}

__global__ __launch_bounds__(256) void ln_unf_inter(
    const float* __restrict__ in, const float* __restrict__ g,
    const float* __restrict__ be, unsigned short* __restrict__ unf)
{
  int bt = blockIdx.x; int b = bt >> 9, t = bt & 511;
  __shared__ float v[48][66];
  __shared__ float mu[65], rs[65];
  __shared__ float g_l[48], b_l[48];
  const float* base = in + (size_t)b*(48*512*65) + (size_t)t*65;
  for (int i = threadIdx.x; i < 48*65; i += 256){
    int c = i/65, q = i - c*65;
    v[c][q] = base[(size_t)c*(512*65) + q];
  }
  if (threadIdx.x < 48){ g_l[threadIdx.x] = g[threadIdx.x]; b_l[threadIdx.x] = be[threadIdx.x]; }
  __syncthreads();
  if (threadIdx.x < 65){
    int q = threadIdx.x; float s=0.f, s2=0.f;
    #pragma unroll
    for (int c = 0; c < 48; c++){ float x = v[c][q]; s += x; s2 += x*x; }
    float m = s*(1.0f/48.0f);
    mu[q] = m; rs[q] = rsqrtf(s2*(1.0f/48.0f) - m*m + 1e-5f);
  }
  __syncthreads();
  for (int idx = threadIdx.x; idx < 4*65*6; idx += 256){
    int s = idx/390;
    int rem = idx - s*390;
    int q = rem/6, c0 = (rem - q*6)*8;
    int l = t - 3 + s, kk = 3 - s;
    if (l < 0 || l > 508) continue;
    float mq = mu[q], rq = rs[q];
    ushort4 p0, p1;
    p0.x = f2bf((v[c0+0][q]-mq)*rq*g_l[c0+0] + b_l[c0+0]);
    p0.y = f2bf((v[c0+1][q]-mq)*rq*g_l[c0+1] + b_l[c0+1]);
    p0.z = f2bf((v[c0+2][q]-mq)*rq*g_l[c0+2] + b_l[c0+2]);
    p0.w = f2bf((v[c0+3][q]-mq)*rq*g_l[c0+3] + b_l[c0+3]);
    p1.x = f2bf((v[c0+4][q]-mq)*rq*g_l[c0+4] + b_l[c0+4]);
    p1.y = f2bf((v[c0+5][q]-mq)*rq*g_l[c0+5] + b_l[c0+5]);
    p1.z = f2bf((v[c0+6][q]-mq)*rq*g_l[c0+6] + b_l[c0+6]);
    p1.w = f2bf((v[c0+7][q]-mq)*rq*g_l[c0+7] + b_l[c0+7]);
    size_t addr = ((size_t)(b*65+q)*509 + l)*192 + kk*48 + c0;
    *(ushort4*)(unf + addr) = p0;
    *(ushort4*)(unf + addr + 4) = p1;
  }
}

// ---------------- GEMM: xg = unf @ Wi^T + bias (standalone, prologue window) ----------------
__global__ __launch_bounds__(256) void gemm_xg(
    const unsigned short* __restrict__ unf, const unsigned short* __restrict__ wib,
    const float* __restrict__ bias, unsigned short* __restrict__ xg,
    int NSEQ, int TW, int win0, int L, int nvalid)
{
  const int d = blockIdx.z;
  const int lane = threadIdx.x & 63, wave = threadIdx.x >> 6;
  const int kg = lane >> 4, lr = lane & 15;
  const int nslb = TW >> 3;
  const int sb  = blockIdx.x / nslb;
  const int slb = blockIdx.x - sb*nslb;
  const int nbase = blockIdx.y*64;
  const unsigned short* Bp = wib + (size_t)d*768*192;

  const unsigned short* abase[2];
  #pragma unroll
  for (int mt = 0; mt < 2; mt++){
    int sl = slb*8 + wave*2 + mt;
    int s = win0 + sl;
    int l = d ? (L-1-s) : s;
    l = l < 0 ? 0 : (l > L-1 ? L-1 : l);
    int seq = sb*16 + lr;
    seq = seq < nvalid ? seq : nvalid-1;
    abase[mt] = unf + ((size_t)seq*L + l)*192;
  }

  f32x4 acc[2][4] = {};
  #pragma unroll
  for (int kt = 0; kt < 6; kt++){
    int k0 = kt*32 + kg*8;
    bf16x8 a0 = *(const bf16x8*)(abase[0] + k0);
    bf16x8 a1 = *(const bf16x8*)(abase[1] + k0);
    #pragma unroll
    for (int nt = 0; nt < 4; nt++){
      int n = nbase + nt*16 + lr;
      bf16x8 bfr = *(const bf16x8*)(Bp + (size_t)n*192 + k0);
      acc[0][nt] = __builtin_amdgcn_mfma_f32_16x16x32_bf16(a0, bfr, acc[0][nt], 0,0,0);
      acc[1][nt] = __builtin_amdgcn_mfma_f32_16x16x32_bf16(a1, bfr, acc[1][nt], 0,0,0);
    }
  }
  #pragma unroll
  for (int mt = 0; mt < 2; mt++){
    int sl = slb*8 + wave*2 + mt;
    size_t rowb = (((size_t)d*(NSEQ>>4) + sb)*TW + sl)*768;
    #pragma unroll
    for (int nt = 0; nt < 4; nt++){
      int n = nbase + nt*16 + lr;
      float bs = bias[d*768 + n];
      ushort4 pk;
      pk.x = f2bf(acc[mt][nt][0] + bs);
      pk.y = f2bf(acc[mt][nt][1] + bs);
      pk.z = f2bf(acc[mt][nt][2] + bs);
      pk.w = f2bf(acc[mt][nt][3] + bs);
      *(ushort4*)(xg + (rowb + n)*16 + kg*4) = pk;
    }
  }
}

// ---------------- FUSED: recurrence(window w) + xg GEMM(window w+1) ----------------
__global__ __launch_bounds__(768, 3) void fused_rec_xg(
    const unsigned short* __restrict__ xgA,  // [2][NSBR][TW][768][16]
    const unsigned short* __restrict__ whb,  // [2][768][192]
    unsigned short* __restrict__ hs,         // [NSEQ][Qrows][384]
    float* __restrict__ state,               // [2][NSEQ][2][192]
    const unsigned short* __restrict__ unf,
    const unsigned short* __restrict__ wib,
    const float* __restrict__ bias,
    unsigned short* __restrict__ xgB,
    int NSEQ, int TW, int win0, int L, int Qrows, int nvalid, int steps,
    int NR, int NSBR, int NSLB, int win0x)
{
  const int tid = threadIdx.x;
  const int lane = tid & 63, w = tid >> 6;
  const int kg = lane >> 4, lr = lane & 15;

  __shared__ unsigned short h_lds[2][16][200];

  if ((int)blockIdx.x >= NR){
    // ---- xg role ----
    int e = blockIdx.x - NR;
    int nb = e % 12; e /= 12;
    int slb = e % NSLB; e /= NSLB;
    int sb = e % NSBR; int d = e / NSBR;
    int sl = slb*12 + w;
    if (sl >= TW) return;
    int s = win0x + sl;
    int l = d ? (L-1-s) : s;
    l = l < 0 ? 0 : (l > L-1 ? L-1 : l);
    int seq = sb*16 + lr;
    seq = seq < nvalid ? seq : nvalid-1;
    const unsigned short* ab = unf + ((size_t)seq*L + l)*192;
    const unsigned short* Bp = wib + (size_t)d*768*192;
    const int nbase = nb*64;
    f32x4 acc[4] = {};
    #pragma unroll
    for (int kt = 0; kt < 6; kt++){
      int k0 = kt*32 + kg*8;
      bf16x8 a = *(const bf16x8*)(ab + k0);
      #pragma unroll
      for (int nt = 0; nt < 4; nt++){
        bf16x8 bfr = *(const bf16x8*)(Bp + (size_t)(nbase+nt*16+lr)*192 + k0);
        acc[nt] = __builtin_amdgcn_mfma_f32_16x16x32_bf16(a, bfr, acc[nt], 0,0,0);
      }
    }
    size_t rowb = (((size_t)d*NSBR + sb)*TW + sl)*768;
    #pragma unroll
    for (int nt = 0; nt < 4; nt++){
      int n = nbase + nt*16 + lr;
      float bs = bias[d*768 + n];
      ushort4 pk;
      pk.x = f2bf(acc[nt][0] + bs);
      pk.y = f2bf(acc[nt][1] + bs);
      pk.z = f2bf(acc[nt][2] + bs);
      pk.w = f2bf(acc[nt][3] + bs);
      *(ushort4*)(xgB + (rowb + n)*16 + kg*4) = pk;
    }
    return;
  }

  // ---- recurrence role ----
  const int d = blockIdx.x / NSBR;
  const int sbx = blockIdx.x - d*NSBR;
  const int seq0 = sbx * 16;
  const int col = w*16 + lr;

  bf16x8 whf[4][6];
  #pragma unroll
  for (int g = 0; g < 4; g++){
    const unsigned short* wrow = whb + ((size_t)d*768 + g*192 + col)*192;
    #pragma unroll
    for (int kt = 0; kt < 6; kt++)
      whf[g][kt] = *(const bf16x8*)(wrow + kt*32 + kg*8);
  }

  float c_reg[4];
  unsigned short* hsp[4];
  bool val[4];
  const int l0 = d ? (L-1-win0) : win0;
  const ptrdiff_t ldelta = d ? -384 : 384;
  #pragma unroll
  for (int r = 0; r < 4; r++){
    int m = kg*4 + r;
    const float* st = state + (((size_t)d*NSEQ + seq0 + m)*2)*192;
    h_lds[0][m][col] = f2bf(st[col]);
    c_reg[r] = st[192 + col];
    val[r] = (seq0 + m) < nvalid;
    hsp[r] = hs + ((size_t)(seq0+m)*Qrows + (l0+3))*384 + d*192 + col;
  }
  lds_barrier();

  const unsigned short* xq0 = xgA + ((((size_t)d*NSBR + sbx)*TW)*768)*16
                              + ((size_t)col)*16 + kg*4;
  const size_t SSTR = (size_t)768*16;

  uint2 pfA[4], pfB[4];
  {
    const unsigned short* p1 = xq0 + (steps > 1 ? SSTR : 0);
    #pragma unroll
    for (int g = 0; g < 4; g++){
      pfA[g] = *(const uint2*)(xq0 + (size_t)g*(192*16));
      pfB[g] = *(const uint2*)(p1  + (size_t)g*(192*16));
    }
  }

  int cur = 0;
  auto do_step = [&](uint2 (&pf)[4], int ss){
    f32x4 acc[4];
    #pragma unroll
    for (int g = 0; g < 4; g++){
      unsigned int lo = pf[g].x, hi = pf[g].y;
      acc[g][0] = b2f((unsigned short)(lo & 0xffffu));
      acc[g][1] = b2f((unsigned short)(lo >> 16));
      acc[g][2] = b2f((unsigned short)(hi & 0xffffu));
      acc[g][3] = b2f((unsigned short)(hi >> 16));
    }
    int nss = ss + 2; nss = nss > steps-1 ? steps-1 : nss;
    const unsigned short* np = xq0 + (size_t)nss*SSTR;
    #pragma unroll
    for (int g = 0; g < 4; g++)
      pf[g] = *(const uint2*)(np + (size_t)g*(192*16));
    #pragma unroll
    for (int kt = 0; kt < 6; kt++){
      bf16x8 a = *(const bf16x8*)(&h_lds[cur][lr][kt*32 + kg*8]);
      #pragma unroll
      for (int g = 0; g < 4; g++)
        acc[g] = __builtin_amdgcn_mfma_f32_16x16x32_bf16(a, whf[g][kt], acc[g], 0,0,0);
    }
    #pragma unroll
    for (int r = 0; r < 4; r++){
      float gi = sig2(acc[0][r]);
      float gf = sig2(acc[1][r]);
      float gg = tanh2s(acc[2][r]);
      float go = sig2(acc[3][r]);
      float c = gf*c_reg[r] + gi*gg;
      c_reg[r] = c;
      float h = go*tanh_n(c);
      unsigned short hb = f2bf(h);
      h_lds[cur^1][kg*4 + r][col] = hb;
      if (val[r]) __builtin_nontemporal_store(hb, hsp[r]);
      hsp[r] += ldelta;
    }
    lds_barrier();
    cur ^= 1;
  };

  for (int ss = 0; ss < steps; ss += 2){
    do_step(pfA, ss);
    if (ss + 1 < steps) do_step(pfB, ss + 1);
  }

  #pragma unroll
  for (int r = 0; r < 4; r++){
    int m = kg*4 + r;
    float* st = state + (((size_t)d*NSEQ + seq0 + m)*2)*192;
    st[col] = b2f(h_lds[cur][m][col]);
    st[192 + col] = c_reg[r];
  }
}

// ---------------- convT as GEMM: K-split B staging (2 phases, 73.7KB LDS -> 2 blocks/CU) ----------------
template<int MODE>
__global__ __launch_bounds__(512) void gemm_convt(
    const unsigned short* __restrict__ hs, const unsigned short* __restrict__ lwt2,
    const float* __restrict__ lb, const float* __restrict__ addsrc, float* __restrict__ dst)
{
  constexpr int Q  = MODE ? 512 : 65;
  const int lane = threadIdx.x & 63, wave = threadIdx.x >> 6;   // 8 waves
  const int kg = lane >> 4, lr = lane & 15;
  const int R0 = blockIdx.x * 128;

  __shared__ union __align__(16) U {
    unsigned short b[96*48*8];   // 73,728 B
    float c[128][53];
  } sm;

  const int row = R0 + wave*16 + lr;
  const int an = row / Q, aq = row - an*Q;

  f32x4 acc[3] = {};
  #pragma unroll
  for (int p = 0; p < 2; p++){
    if (p) __syncthreads();
    for (int cidx = threadIdx.x; cidx < 4608; cidx += 512)
      *(uint4*)&sm.b[(size_t)cidx*8] = *(const uint4*)(lwt2 + ((size_t)p*4608 + cidx)*8);
    __syncthreads();

    const unsigned short* ab0 = hs + ((size_t)an*(Q+3) + aq + 3 - p*2)*384 + kg*8;
    const unsigned short* ab1 = ab0 - 384;

    bf16x8 pfA = *(const bf16x8*)(ab0);
    bf16x8 pfB = *(const bf16x8*)(ab0 + 32);
    bf16x8 pfC = *(const bf16x8*)(ab0 + 64);
    for (int kt = 0; kt < 24; kt++){
      bf16x8 a = pfA; pfA = pfB; pfB = pfC;
      int nk = kt + 3;
      if (nk < 24)
        pfC = *(const bf16x8*)((nk < 12) ? (ab0 + nk*32) : (ab1 + (nk-12)*32));
      const int bo = (kt*4 + kg)*48*8;
      #pragma unroll
      for (int nt = 0; nt < 3; nt++){
        bf16x8 bfr = *(const bf16x8*)&sm.b[bo + (nt*16 + lr)*8];
        acc[nt] = __builtin_amdgcn_mfma_f32_16x16x32_bf16(a, bfr, acc[nt], 0,0,0);
      }
    }
  }

  if (MODE == 0){
    __syncthreads();
    #pragma unroll
    for (int nt = 0; nt < 3; nt++)
      #pragma unroll
      for (int r = 0; r < 4; r++)
        sm.c[wave*16 + kg*4 + r][nt*16 + lr] = acc[nt][r];
    __syncthreads();
    const int b = R0 >= 33280 ? 1 : 0;
    const size_t bb = (size_t)b*1597440;
    const int rb = R0 - b*33280;
    for (int idx = threadIdx.x; idx < 48*32; idx += 512){
      int n = idx >> 5, g = idx & 31;
      size_t off = bb + (size_t)n*33280 + rb + g*4;
      float4 av = *(const float4*)(addsrc + off);
      float lbn = lb[n];
      float4 o;
      o.x = sm.c[g*4+0][n] + lbn + av.x;
      o.y = sm.c[g*4+1][n] + lbn + av.y;
      o.z = sm.c[g*4+2][n] + lbn + av.z;
      o.w = sm.c[g*4+3][n] + lbn + av.w;
      *(float4*)(dst + off) = o;
    }
  } else {
    #pragma unroll
    for (int nt = 0; nt < 3; nt++){
      int n = nt*16 + lr;
      float lbn = lb[n];
      #pragma unroll
      for (int r = 0; r < 4; r++){
        int orow = R0 + wave*16 + kg*4 + r;
        int ns = orow >> 9, t = orow & 511;
        size_t off = (size_t)(ns/65)*1597440 + (size_t)n*33280 + (ns%65) + (size_t)t*65;
        dst[off] = acc[nt][r] + lbn + addsrc[off];
      }
    }
  }
}

// ---------------- generic row-major bf16 GEMM (BT layout), batched ----------------
__global__ __launch_bounds__(256) void gemm_rm(
    const unsigned short* __restrict__ A, const unsigned short* __restrict__ B, float* __restrict__ C,
    int lda, int ldb, int ldc, int KT, int nmax, long long strA, long long strB, long long strC)
{
  const int z = blockIdx.z;
  A += (size_t)z * strA; B += (size_t)z * strB; C += (size_t)z * strC;
  const int lane = threadIdx.x & 63, wave = threadIdx.x >> 6;
  const int kg = lane >> 4, lr = lane & 15;
  const int rowbase = blockIdx.x*128 + wave*32;
  const int nbase = blockIdx.y*64;
  f32x4 acc[2][4] = {};
  for (int kt = 0; kt < KT; kt++){
    int k0 = kt*32 + kg*8;
    bf16x8 a0 = *(const bf16x8*)(A + (size_t)(rowbase+lr)*lda + k0);
    bf16x8 a1 = *(const bf16x8*)(A + (size_t)(rowbase+16+lr)*lda + k0);
    #pragma unroll
    for (int nt = 0; nt < 4; nt++){
      bf16x8 bfr = *(const bf16x8*)(B + (size_t)(nbase+nt*16+lr)*ldb + k0);
      acc[0][nt] = __builtin_amdgcn_mfma_f32_16x16x32_bf16(a0, bfr, acc[0][nt], 0,0,0);
      acc[1][nt] = __builtin_amdgcn_mfma_f32_16x16x32_bf16(a1, bfr, acc[1][nt], 0,0,0);
    }
  }
  #pragma unroll
  for (int mt = 0; mt < 2; mt++)
  #pragma unroll
  for (int nt = 0; nt < 4; nt++)
  #pragma unroll
  for (int r = 0; r < 4; r++){
    int n = nbase + nt*16 + lr;
    if (n < nmax){
      int row = rowbase + mt*16 + kg*4 + r;
      C[(size_t)row*ldc + n] = acc[mt][nt][r];
    }
  }
}

// ---------------- FUSED qkv projection + prelu + LN over (e,f): float4 LDS ----------------
// in_t transposed [65][48] so the c-axis is contiguous; inner loop = 12x{2x b128 + 4 FMA}.
__global__ __launch_bounds__(256) void qkv3_k(
    const float* __restrict__ inter,
    const float* __restrict__ qw, const float* __restrict__ qb, const float* __restrict__ qa,
    const float* __restrict__ qg, const float* __restrict__ qbe,
    const float* __restrict__ kw, const float* __restrict__ kb, const float* __restrict__ ka,
    const float* __restrict__ kgm, const float* __restrict__ kbe,
    const float* __restrict__ vw, const float* __restrict__ vb, const float* __restrict__ va,
    const float* __restrict__ vg, const float* __restrict__ vbe,
    unsigned short* __restrict__ q2b, unsigned short* __restrict__ k2b,
    unsigned short* __restrict__ v2t)
{
  int t = blockIdx.x; int hb = blockIdx.y; int h = hb >> 1, b = hb & 1;
  __shared__ __align__(16) float in_t[65][48];
  __shared__ __align__(16) float w_l[28][48];
  __shared__ float y_l[780];
  __shared__ float rs1[4], rs2[4];
  const float* base = inter + (size_t)b*(48*512*65) + (size_t)t*65;
  for (int i = threadIdx.x; i < 48*65; i += 256){
    int c = i/65, q = i - c*65;
    in_t[q][c] = base[(size_t)c*(512*65) + q];
  }
  for (int i = threadIdx.x; i < 8*48; i += 256)  w_l[i/48][i%48]      = qw[(size_t)h*8*48 + i];
  for (int i = threadIdx.x; i < 8*48; i += 256)  w_l[8 + i/48][i%48]  = kw[(size_t)h*8*48 + i];
  for (int i = threadIdx.x; i < 12*48; i += 256) w_l[16 + i/48][i%48] = vw[(size_t)h*12*48 + i];
  __syncthreads();

  #pragma unroll
  for (int ph = 0; ph < 3; ph++){
    const int E   = (ph == 2) ? 12 : 8;
    const int wo  = (ph == 0) ? 0 : (ph == 1 ? 8 : 16);
    const float* bias  = (ph == 0) ? qb  : (ph == 1 ? kb  : vb);
    const float* alpha = (ph == 0) ? qa  : (ph == 1 ? ka  : va);
    const float* gam   = (ph == 0) ? qg  : (ph == 1 ? kgm : vg);
    const float* bet   = (ph == 0) ? qbe : (ph == 1 ? kbe : vbe);
    int nel = E*65;
    float a = alpha[h];
    float ps = 0.f, pq = 0.f;
    for (int i = threadIdx.x; i < nel; i += 256){
      int e = i/65, f = i - e*65;
      float s = bias[h*E + e];
      const float4* wr = (const float4*)&w_l[wo + e][0];
      const float4* xr = (const float4*)&in_t[f][0];
      #pragma unroll
      for (int c4 = 0; c4 < 12; c4++){
        float4 wv = wr[c4], xv = xr[c4];
        s += wv.x*xv.x + wv.y*xv.y + wv.z*xv.z + wv.w*xv.w;
      }
      s = s >= 0.f ? s : a*s;
      y_l[i] = s; ps += s; pq += s*s;
    }
    #pragma unroll
    for (int o = 32; o; o >>= 1){ ps += __shfl_xor(ps, o); pq += __shfl_xor(pq, o); }
    if ((threadIdx.x & 63) == 0){ rs1[threadIdx.x>>6] = ps; rs2[threadIdx.x>>6] = pq; }
    __syncthreads();
    ps = rs1[0]+rs1[1]+rs1[2]+rs1[3]; pq = rs2[0]+rs2[1]+rs2[2]+rs2[3];
    float inv = 1.0f/(float)nel;
    float m = ps*inv; float rstd = rsqrtf(pq*inv - m*m + 1e-5f);
    for (int i = threadIdx.x; i < nel; i += 256){
      int e = i/65, f = i - e*65;
      float v = (y_l[i]-m)*rstd*gam[(size_t)(h*E+e)*65 + f] + bet[(size_t)(h*E+e)*65 + f];
      if (ph == 0)      q2b[((size_t)hb*512 + t)*544 + i] = f2bf(v);
      else if (ph == 1) k2b[((size_t)hb*512 + t)*544 + i] = f2bf(v);
      else              v2t[((size_t)hb*832 + i)*512 + t] = f2bf(v);
    }
    __syncthreads();
  }
}

// ---------------- softmax over rows of 512 ----------------
__global__ __launch_bounds__(256) void softmax_k(const float* __restrict__ S, unsigned short* __restrict__ P){
  size_t row = (size_t)blockIdx.y*512 + blockIdx.x;
  const float* s = S + row*512;
  int tid = threadIdx.x;
  float v0 = s[tid], v1 = s[tid+256];
  float m = fmaxf(v0, v1);
  #pragma unroll
  for (int o = 32; o; o >>= 1) m = fmaxf(m, __shfl_xor(m, o));
  __shared__ float r4[4], q4[4];
  if ((tid & 63) == 0) r4[tid>>6] = m;
  __syncthreads();
  m = fmaxf(fmaxf(r4[0], r4[1]), fmaxf(r4[2], r4[3]));
  const float sc = 0.04385290096535146f;  // 1/sqrt(520)
  float e0 = __expf((v0-m)*sc), e1 = __expf((v1-m)*sc);
  float su = e0 + e1;
  #pragma unroll
  for (int o = 32; o; o >>= 1) su += __shfl_xor(su, o);
  if ((tid & 63) == 0) q4[tid>>6] = su;
  __syncthreads();
  su = q4[0]+q4[1]+q4[2]+q4[3];
  float inv = __builtin_amdgcn_rcpf(su);
  unsigned short* p = P + row*512;
  p[tid] = f2bf(e0*inv); p[tid+256] = f2bf(e1*inv);
}

// ---------------- final projection + prelu + LN over (c,f) + residual ----------------
__global__ __launch_bounds__(256) void pout_k(
    const float* __restrict__ o, const float* __restrict__ pw, const float* __restrict__ pb,
    const float* __restrict__ pa, const float* __restrict__ pg, const float* __restrict__ pbe,
    const float* __restrict__ inter, float* __restrict__ out)
{
  int bt = blockIdx.x; int b = bt >> 9, t = bt & 511;
  __shared__ float o_l[48][66];
  __shared__ float pw_l[48][48];
  __shared__ float p_l[3120];
  __shared__ float rs1[4], rs2[4];
  for (int i = threadIdx.x; i < 48*65; i += 256){
    int c = i/65, f = i - c*65; int h = c/12, dd = c - h*12;
    o_l[c][f] = o[((size_t)(h*2+b)*512 + t)*780 + dd*65 + f];
  }
  for (int i = threadIdx.x; i < 48*48; i += 256) pw_l[i/48][i - (i/48)*48] = pw[i];
  __syncthreads();
  float a = pa[0];
  float ps = 0.f, pq = 0.f;
  for (int i = threadIdx.x; i < 3120; i += 256){
    int oc = i/65, f = i - oc*65;
    float s = pb[oc];
    #pragma unroll
    for (int c = 0; c < 48; c++) s += pw_l[oc][c]*o_l[c][f];
    s = s >= 0.f ? s : a*s;
    p_l[i] = s; ps += s; pq += s*s;
  }
  #pragma unroll
  for (int o2 = 32; o2; o2 >>= 1){ ps += __shfl_xor(ps, o2); pq += __shfl_xor(pq, o2); }
  if ((threadIdx.x & 63) == 0){ rs1[threadIdx.x>>6] = ps; rs2[threadIdx.x>>6] = pq; }
  __syncthreads();
  ps = rs1[0]+rs1[1]+rs1[2]+rs1[3]; pq = rs2[0]+rs2[1]+rs2[2]+rs2[3];
  float m = ps*(1.0f/3120.0f); float rstd = rsqrtf(pq*(1.0f/3120.0f) - m*m + 1e-5f);
  for (int i = threadIdx.x; i < 3120; i += 256){
    int oc = i/65, f = i - oc*65;
    size_t off = ((size_t)(b*48+oc)*512 + t)*65 + f;
    out[off] = (p_l[i]-m)*rstd*pg[i] + pbe[i] + inter[off];
  }
}

// ---------------- launch ----------------

extern "C" void kernel_launch(void* const* d_in, const int* in_sizes, int n_in,
                              void* d_out, int out_size, void* d_ws, size_t ws_size,
                              hipStream_t stream)
{
  const float* x         = (const float*)d_in[0];
  const float* intra_g   = (const float*)d_in[2];
  const float* intra_b   = (const float*)d_in[3];
  const float* intra_wih = (const float*)d_in[4];
  const float* intra_whh = (const float*)d_in[5];
  const float* intra_bih = (const float*)d_in[6];
  const float* intra_bhh = (const float*)d_in[7];
  const float* intra_lw  = (const float*)d_in[8];
  const float* intra_lb  = (const float*)d_in[9];
  const float* inter_g   = (const float*)d_in[10];
  const float* inter_b   = (const float*)d_in[11];
  const float* inter_wih = (const float*)d_in[12];
  const float* inter_whh = (const float*)d_in[13];
  const float* inter_bih = (const float*)d_in[14];
  const float* inter_bhh = (const float*)d_in[15];
  const float* inter_lw  = (const float*)d_in[16];
  const float* inter_lb  = (const float*)d_in[17];
  const float* qw  = (const float*)d_in[18];
  const float* qb  = (const float*)d_in[19];
  const float* qa  = (const float*)d_in[20];
  const float* qg  = (const float*)d_in[21];
  const float* qbe = (const float*)d_in[22];
  const float* kw  = (const float*)d_in[23];
  const float* kb  = (const float*)d_in[24];
  const float* ka  = (const float*)d_in[25];
  const float* kgm = (const float*)d_in[26];
  const float* kbe = (const float*)d_in[27];
  const float* vw  = (const float*)d_in[28];
  const float* vb  = (const float*)d_in[29];
  const float* va  = (const float*)d_in[30];
  const float* vg  = (const float*)d_in[31];
  const float* vbe = (const float*)d_in[32];
  const float* pw  = (const float*)d_in[33];
  const float* pb  = (const float*)d_in[34];
  const float* pa  = (const float*)d_in[35];
  const float* pgm = (const float*)d_in[36];
  const float* pbe = (const float*)d_in[37];

  char* ws = (char*)d_ws;
  constexpr size_t WIB_INTRA = 0;
  constexpr size_t WHB_INTRA = 589824;
  constexpr size_t WIB_INTER = 1179648;
  constexpr size_t WHB_INTER = 1769472;
  constexpr size_t LWT_INTRA = 2359296;
  constexpr size_t LWT_INTER = 2555904;
  constexpr size_t BIAS_INTRA = 2752512;
  constexpr size_t BIAS_INTER = 2758656;
  constexpr size_t UNF   = 2764800;
  constexpr size_t INTER = 2764800;            // alias: written only after UNF is dead
  constexpr size_t STATE = 28311552;
  constexpr size_t HS    = 31457280;
  constexpr size_t INTRA = 84934656;
  constexpr size_t XG    = 97714176;           // double-buffered region (50,331,648 B)
  constexpr size_t Q2B   = XG;
  constexpr size_t K2B   = XG + 4456448;
  constexpr size_t V2T   = XG + 8912896;
  constexpr size_t SCORES= XG + 15728640;
  constexpr size_t ATTNB = XG + 24117248;
  constexpr size_t OBUF  = XG + 28311552;

  auto U16 = [&](size_t off){ return (unsigned short*)(ws + off); };
  auto F32 = [&](size_t off){ return (float*)(ws + off); };

  // ---- prep (single dispatch) ----
  prep_all<<<5197,256,0,stream>>>(intra_wih, intra_whh, inter_wih, inter_whh,
                                  intra_bih, intra_bhh, inter_bih, inter_bhh,
                                  intra_lw, inter_lw,
                                  U16(WIB_INTRA), U16(WHB_INTRA), U16(WIB_INTER), U16(WHB_INTER),
                                  F32(BIAS_INTRA), F32(BIAS_INTER),
                                  U16(LWT_INTRA), U16(LWT_INTER));

  // ---- intra stage (TW=8, 8 windows, xg fused with rec) ----
  {
    unsigned short* xb[2] = { U16(XG), U16(XG + 25165824) };
    ln_unf_intra<<<1024,256,0,stream>>>(x, intra_g, intra_b, U16(UNF));
    zero_stage<<<9984,256,0,stream>>>(U16(HS), 1024, 68, 62, (uint4*)(ws+STATE));
    gemm_xg<<<dim3(64,12,2),256,0,stream>>>(U16(UNF), U16(WIB_INTRA), F32(BIAS_INTRA), xb[0],
                                            1024, 8, 0, 62, 1024);
    for (int w = 0; w < 8; w++){
      int win0 = w*8;
      int steps = (62 - win0) < 8 ? (62 - win0) : 8;
      int nxg = (w < 7) ? 1536 : 0;   // 2 dirs x 64 sb x 1 slb x 12 nb
      fused_rec_xg<<<128 + nxg, 768, 0, stream>>>(
          xb[w&1], U16(WHB_INTRA), U16(HS), F32(STATE),
          U16(UNF), U16(WIB_INTRA), F32(BIAS_INTRA), xb[(w+1)&1],
          1024, 8, win0, 62, 68, 1024, steps,
          128, 64, 1, (w+1)*8);
    }
    gemm_convt<0><<<520,512,0,stream>>>(U16(HS), U16(LWT_INTRA), intra_lb, x, F32(INTRA));
  }

  // ---- inter stage (TW=48, 11 windows, xg fused with rec) ----
  {
    unsigned short* xb[2] = { U16(XG), U16(XG + 21233664) };
    ln_unf_inter<<<1024,256,0,stream>>>(F32(INTRA), inter_g, inter_b, U16(UNF));
    zero_stage<<<1938,256,0,stream>>>(U16(HS), 130, 515, 509, (uint4*)(ws+STATE));
    gemm_xg<<<dim3(54,12,2),256,0,stream>>>(U16(UNF), U16(WIB_INTER), F32(BIAS_INTER), xb[0],
                                            144, 48, 0, 509, 130);
    for (int w = 0; w < 11; w++){
      int win0 = w*48;
      int steps = (509 - win0) < 48 ? (509 - win0) : 48;
      int nxg = (w < 10) ? 864 : 0;   // 2 dirs x 9 sb x 4 slb x 12 nb
      fused_rec_xg<<<18 + nxg, 768, 0, stream>>>(
          xb[w&1], U16(WHB_INTER), U16(HS), F32(STATE),
          U16(UNF), U16(WIB_INTER), F32(BIAS_INTER), xb[(w+1)&1],
          144, 48, win0, 509, 515, 130, steps,
          18, 9, 4, (w+1)*48);
    }
    gemm_convt<1><<<520,512,0,stream>>>(U16(HS), U16(LWT_INTER), inter_lb, F32(INTRA), F32(INTER));
  }

  // ---- attention stage ----
  zero16<<<2048,256,0,stream>>>((uint4*)(ws+Q2B), 15728640/16);
  qkv3_k<<<dim3(512,8),256,0,stream>>>(F32(INTER),
                                       qw, qb, qa, qg, qbe,
                                       kw, kb, ka, kgm, kbe,
                                       vw, vb, va, vg, vbe,
                                       U16(Q2B), U16(K2B), U16(V2T));
  gemm_rm<<<dim3(4,8,8),256,0,stream>>>(U16(Q2B), U16(K2B), F32(SCORES),
                                        544, 544, 512, 17, 512,
                                        (long long)512*544, (long long)512*544, (long long)512*512);
  softmax_k<<<dim3(512,8),256,0,stream>>>(F32(SCORES), U16(ATTNB));
  gemm_rm<<<dim3(4,13,8),256,0,stream>>>(U16(ATTNB), U16(V2T), F32(OBUF),
                                         512, 512, 780, 16, 780,
                                         (long long)512*512, (long long)832*512, (long long)512*780);
  pout_k<<<1024,256,0,stream>>>(F32(OBUF), pw, pb, pa, pgm, pbe, F32(INTER), (float*)d_out);
}

// Round 14
// 1603.636 us; speedup vs baseline: 1.0139x; 1.0139x over previous
//
#include <hip/hip_runtime.h>
#include <hip/hip_bf16.h>

typedef __bf16 bf16x8 __attribute__((ext_vector_type(8)));
typedef unsigned short u16x8 __attribute__((ext_vector_type(8)));
typedef float f32x4 __attribute__((ext_vector_type(4)));

#define DEV static __device__ __forceinline__

DEV unsigned short f2bf(float f){
  __hip_bfloat16 h = __float2bfloat16(f);
  return __builtin_bit_cast(unsigned short, h);
}
DEV float b2f(unsigned short u){
  return __bfloat162float(__builtin_bit_cast(__hip_bfloat16, u));
}
// gate math in exp2 domain: inputs pre-scaled by log2(e)
DEV float sig2(float xs){
  return __builtin_amdgcn_rcpf(1.0f + __builtin_amdgcn_exp2f(-xs));
}
DEV float tanh2s(float xs){
  return 1.0f - 2.0f*__builtin_amdgcn_rcpf(__builtin_amdgcn_exp2f(xs + xs) + 1.0f);
}
DEV float tanh_n(float x){
  return 1.0f - 2.0f*__builtin_amdgcn_rcpf(__builtin_amdgcn_exp2f(x * 2.885390082f) + 1.0f);
}
DEV void lds_barrier(){
  asm volatile("s_waitcnt lgkmcnt(0)\ns_barrier" ::: "memory");
}

// ---------------- utility kernels ----------------

__global__ void zero16(uint4* p, size_t n){
  size_t i = (size_t)blockIdx.x*blockDim.x + threadIdx.x;
  size_t st = (size_t)gridDim.x*blockDim.x;
  uint4 z = make_uint4(0u,0u,0u,0u);
  for (; i < n; i += st) p[i] = z;
}

// combined: zero hs conv-pad rows + STATE buffer (one dispatch per stage)
__global__ void zero_stage(unsigned short* hs, int NSEQ, int Qrows, int L, uint4* state){
  int i = blockIdx.x*256 + threadIdx.x;
  int padsN = NSEQ*6*384;
  if (i < padsN){
    int t = i/(6*384); int rem = i - t*(6*384);
    int r = rem/384, c = rem - r*384;
    int row = r < 3 ? r : L + r;
    hs[((size_t)t*Qrows + row)*384 + c] = 0;
  } else {
    int j = i - padsN;
    if (j < 196608) state[j] = make_uint4(0u,0u,0u,0u);
  }
}

// ---------------- fused prep: weight casts (log2e-scaled), bias combine, lwt build ----------------
__global__ void prep_all(
    const float* __restrict__ intra_wih, const float* __restrict__ intra_whh,
    const float* __restrict__ inter_wih, const float* __restrict__ inter_whh,
    const float* __restrict__ intra_bih, const float* __restrict__ intra_bhh,
    const float* __restrict__ inter_bih, const float* __restrict__ inter_bhh,
    const float* __restrict__ intra_lw,  const float* __restrict__ inter_lw,
    unsigned short* __restrict__ wib_a, unsigned short* __restrict__ whb_a,
    unsigned short* __restrict__ wib_e, unsigned short* __restrict__ whb_e,
    float* __restrict__ bias_a, float* __restrict__ bias_e,
    unsigned short* __restrict__ lwt_a, unsigned short* __restrict__ lwt_e)
{
  const float LOG2E = 1.4426950408889634f;
  int i = blockIdx.x*256 + threadIdx.x;
  if (i < 294912){
    int dn = i/192, k = i - dn*192;
    int c = k >> 2, kk = k & 3;
    wib_a[(size_t)dn*192 + kk*48 + c] = f2bf(intra_wih[i]*LOG2E);
  } else if (i < 589824){
    int j = i - 294912;
    whb_a[j] = f2bf(intra_whh[j]*LOG2E);
  } else if (i < 884736){
    int j = i - 589824;
    int dn = j/192, k = j - dn*192;
    int c = k >> 2, kk = k & 3;
    wib_e[(size_t)dn*192 + kk*48 + c] = f2bf(inter_wih[j]*LOG2E);
  } else if (i < 1179648){
    int j = i - 884736;
    whb_e[j] = f2bf(inter_whh[j]*LOG2E);
  } else if (i < 1181184){
    int j = i - 1179648;
    bias_a[j] = (intra_bih[j] + intra_bhh[j])*LOG2E;
  } else if (i < 1182720){
    int j = i - 1181184;
    bias_e[j] = (inter_bih[j] + inter_bhh[j])*LOG2E;
  } else if (i < 1256448){
    int j = i - 1182720;
    int m = j / 192; int rest = j - m*192; int c = rest >> 2; int k = rest & 3;
    int kap = k*384 + m;
    lwt_a[((size_t)(kap>>3)*48 + c)*8 + (kap&7)] = f2bf(intra_lw[j]);
  } else if (i < 1330176){
    int j = i - 1256448;
    int m = j / 192; int rest = j - m*192; int c = rest >> 2; int k = rest & 3;
    int kap = k*384 + m;
    lwt_e[((size_t)(kap>>3)*48 + c)*8 + (kap&7)] = f2bf(inter_lw[j]);
  }
}

// ---------------- LN over C + unfold -> bf16 unf[seq][l][kk*48+c] ----------------
__global__ __launch_bounds__(256) void ln_unf_intra(
    const float* __restrict__ in, const float* __restrict__ g,
    const float* __restrict__ be, unsigned short* __restrict__ unf)
{
  int bt = blockIdx.x; int b = bt >> 9, t = bt & 511;
  __shared__ float v[48][66];
  __shared__ float mu[65], rs[65];
  __shared__ float g_l[48], b_l[48];
  const float* base = in + (size_t)b*(48*512*65) + (size_t)t*65;
  for (int i = threadIdx.x; i < 48*65; i += 256){
    int c = i/65, q = i - c*65;
    v[c][q] = base[(size_t)c*(512*65) + q];
  }
  if (threadIdx.x < 48){ g_l[threadIdx.x] = g[threadIdx.x]; b_l[threadIdx.x] = be[threadIdx.x]; }
  __syncthreads();
  if (threadIdx.x < 65){
    int q = threadIdx.x; float s=0.f, s2=0.f;
    #pragma unroll
    for (int c = 0; c < 48; c++){ float x = v[c][q]; s += x; s2 += x*x; }
    float m = s*(1.0f/48.0f);
    mu[q] = m; rs[q] = rsqrtf(s2*(1.0f/48.0f) - m*m + 1e-5f);
  }
  __syncthreads();
  unsigned short* orow = unf + (size_t)(b*512 + t)*62*192;
  for (int idx = threadIdx.x; idx < 62*24; idx += 256){
    int l = idx/24, jg = idx - l*24;
    int kk = jg/6, c0 = (jg - kk*6)*8;
    int q = l + kk;
    ushort4 p0, p1;
    float mq = mu[q], rq = rs[q];
    p0.x = f2bf((v[c0+0][q]-mq)*rq*g_l[c0+0] + b_l[c0+0]);
    p0.y = f2bf((v[c0+1][q]-mq)*rq*g_l[c0+1] + b_l[c0+1]);
    p0.z = f2bf((v[c0+2][q]-mq)*rq*g_l[c0+2] + b_l[c0+2]);
    p0.w = f2bf((v[c0+3][q]-mq)*rq*g_l[c0+3] + b_l[c0+3]);
    p1.x = f2bf((v[c0+4][q]-mq)*rq*g_l[c0+4] + b_l[c0+4]);
    p1.y = f2bf((v[c0+5][q]-mq)*rq*g_l[c0+5] + b_l[c0+5]);
    p1.z = f2bf((v[c0+6][q]-mq)*rq*g_l[c0+6] + b_l[c0+6]);
    p1.w = f2bf((v[c0+7][q]-mq)*rq*g_l[c0+7] + b_l[c0+7]);
    *(ushort4*)(orow + (size_t)l*192 + kk*48 + c0) = p0;
    *(ushort4*)(orow + (size_t)l*192 + kk*48 + c0 + 4) = p1;
  }
}

__global__ __launch_bounds__(256) void ln_unf_inter(
    const float* __restrict__ in, const float* __restrict__ g,
    const float* __restrict__ be, unsigned short* __restrict__ unf)
{
  int bt = blockIdx.x; int b = bt >> 9, t = bt & 511;
  __shared__ float v[48][66];
  __shared__ float mu[65], rs[65];
  __shared__ float g_l[48], b_l[48];
  const float* base = in + (size_t)b*(48*512*65) + (size_t)t*65;
  for (int i = threadIdx.x; i < 48*65; i += 256){
    int c = i/65, q = i - c*65;
    v[c][q] = base[(size_t)c*(512*65) + q];
  }
  if (threadIdx.x < 48){ g_l[threadIdx.x] = g[threadIdx.x]; b_l[threadIdx.x] = be[threadIdx.x]; }
  __syncthreads();
  if (threadIdx.x < 65){
    int q = threadIdx.x; float s=0.f, s2=0.f;
    #pragma unroll
    for (int c = 0; c < 48; c++){ float x = v[c][q]; s += x; s2 += x*x; }
    float m = s*(1.0f/48.0f);
    mu[q] = m; rs[q] = rsqrtf(s2*(1.0f/48.0f) - m*m + 1e-5f);
  }
  __syncthreads();
  for (int idx = threadIdx.x; idx < 4*65*6; idx += 256){
    int s = idx/390;
    int rem = idx - s*390;
    int q = rem/6, c0 = (rem - q*6)*8;
    int l = t - 3 + s, kk = 3 - s;
    if (l < 0 || l > 508) continue;
    float mq = mu[q], rq = rs[q];
    ushort4 p0, p1;
    p0.x = f2bf((v[c0+0][q]-mq)*rq*g_l[c0+0] + b_l[c0+0]);
    p0.y = f2bf((v[c0+1][q]-mq)*rq*g_l[c0+1] + b_l[c0+1]);
    p0.z = f2bf((v[c0+2][q]-mq)*rq*g_l[c0+2] + b_l[c0+2]);
    p0.w = f2bf((v[c0+3][q]-mq)*rq*g_l[c0+3] + b_l[c0+3]);
    p1.x = f2bf((v[c0+4][q]-mq)*rq*g_l[c0+4] + b_l[c0+4]);
    p1.y = f2bf((v[c0+5][q]-mq)*rq*g_l[c0+5] + b_l[c0+5]);
    p1.z = f2bf((v[c0+6][q]-mq)*rq*g_l[c0+6] + b_l[c0+6]);
    p1.w = f2bf((v[c0+7][q]-mq)*rq*g_l[c0+7] + b_l[c0+7]);
    size_t addr = ((size_t)(b*65+q)*509 + l)*192 + kk*48 + c0;
    *(ushort4*)(unf + addr) = p0;
    *(ushort4*)(unf + addr + 4) = p1;
  }
}

// ---------------- GEMM: xg = unf @ Wi^T + bias (standalone, prologue window) ----------------
__global__ __launch_bounds__(256) void gemm_xg(
    const unsigned short* __restrict__ unf, const unsigned short* __restrict__ wib,
    const float* __restrict__ bias, unsigned short* __restrict__ xg,
    int NSEQ, int TW, int win0, int L, int nvalid)
{
  const int d = blockIdx.z;
  const int lane = threadIdx.x & 63, wave = threadIdx.x >> 6;
  const int kg = lane >> 4, lr = lane & 15;
  const int nslb = TW >> 3;
  const int sb  = blockIdx.x / nslb;
  const int slb = blockIdx.x - sb*nslb;
  const int nbase = blockIdx.y*64;
  const unsigned short* Bp = wib + (size_t)d*768*192;

  const unsigned short* abase[2];
  #pragma unroll
  for (int mt = 0; mt < 2; mt++){
    int sl = slb*8 + wave*2 + mt;
    int s = win0 + sl;
    int l = d ? (L-1-s) : s;
    l = l < 0 ? 0 : (l > L-1 ? L-1 : l);
    int seq = sb*16 + lr;
    seq = seq < nvalid ? seq : nvalid-1;
    abase[mt] = unf + ((size_t)seq*L + l)*192;
  }

  f32x4 acc[2][4] = {};
  #pragma unroll
  for (int kt = 0; kt < 6; kt++){
    int k0 = kt*32 + kg*8;
    bf16x8 a0 = *(const bf16x8*)(abase[0] + k0);
    bf16x8 a1 = *(const bf16x8*)(abase[1] + k0);
    #pragma unroll
    for (int nt = 0; nt < 4; nt++){
      int n = nbase + nt*16 + lr;
      bf16x8 bfr = *(const bf16x8*)(Bp + (size_t)n*192 + k0);
      acc[0][nt] = __builtin_amdgcn_mfma_f32_16x16x32_bf16(a0, bfr, acc[0][nt], 0,0,0);
      acc[1][nt] = __builtin_amdgcn_mfma_f32_16x16x32_bf16(a1, bfr, acc[1][nt], 0,0,0);
    }
  }
  #pragma unroll
  for (int mt = 0; mt < 2; mt++){
    int sl = slb*8 + wave*2 + mt;
    size_t rowb = (((size_t)d*(NSEQ>>4) + sb)*TW + sl)*768;
    #pragma unroll
    for (int nt = 0; nt < 4; nt++){
      int n = nbase + nt*16 + lr;
      float bs = bias[d*768 + n];
      ushort4 pk;
      pk.x = f2bf(acc[mt][nt][0] + bs);
      pk.y = f2bf(acc[mt][nt][1] + bs);
      pk.z = f2bf(acc[mt][nt][2] + bs);
      pk.w = f2bf(acc[mt][nt][3] + bs);
      *(ushort4*)(xg + (rowb + n)*16 + kg*4) = pk;
    }
  }
}

// ---------------- FUSED: recurrence(window w) + xg GEMM(window w+1) ----------------
__global__ __launch_bounds__(768, 3) void fused_rec_xg(
    const unsigned short* __restrict__ xgA,  // [2][NSBR][TW][768][16]
    const unsigned short* __restrict__ whb,  // [2][768][192]
    unsigned short* __restrict__ hs,         // [NSEQ][Qrows][384]
    float* __restrict__ state,               // [2][NSEQ][2][192]
    const unsigned short* __restrict__ unf,
    const unsigned short* __restrict__ wib,
    const float* __restrict__ bias,
    unsigned short* __restrict__ xgB,
    int NSEQ, int TW, int win0, int L, int Qrows, int nvalid, int steps,
    int NR, int NSBR, int NSLB, int win0x)
{
  const int tid = threadIdx.x;
  const int lane = tid & 63, w = tid >> 6;
  const int kg = lane >> 4, lr = lane & 15;

  __shared__ unsigned short h_lds[2][16][200];

  if ((int)blockIdx.x >= NR){
    // ---- xg role ----
    int e = blockIdx.x - NR;
    int nb = e % 12; e /= 12;
    int slb = e % NSLB; e /= NSLB;
    int sb = e % NSBR; int d = e / NSBR;
    int sl = slb*12 + w;
    if (sl >= TW) return;
    int s = win0x + sl;
    int l = d ? (L-1-s) : s;
    l = l < 0 ? 0 : (l > L-1 ? L-1 : l);
    int seq = sb*16 + lr;
    seq = seq < nvalid ? seq : nvalid-1;
    const unsigned short* ab = unf + ((size_t)seq*L + l)*192;
    const unsigned short* Bp = wib + (size_t)d*768*192;
    const int nbase = nb*64;
    f32x4 acc[4] = {};
    #pragma unroll
    for (int kt = 0; kt < 6; kt++){
      int k0 = kt*32 + kg*8;
      bf16x8 a = *(const bf16x8*)(ab + k0);
      #pragma unroll
      for (int nt = 0; nt < 4; nt++){
        bf16x8 bfr = *(const bf16x8*)(Bp + (size_t)(nbase+nt*16+lr)*192 + k0);
        acc[nt] = __builtin_amdgcn_mfma_f32_16x16x32_bf16(a, bfr, acc[nt], 0,0,0);
      }
    }
    size_t rowb = (((size_t)d*NSBR + sb)*TW + sl)*768;
    #pragma unroll
    for (int nt = 0; nt < 4; nt++){
      int n = nbase + nt*16 + lr;
      float bs = bias[d*768 + n];
      ushort4 pk;
      pk.x = f2bf(acc[nt][0] + bs);
      pk.y = f2bf(acc[nt][1] + bs);
      pk.z = f2bf(acc[nt][2] + bs);
      pk.w = f2bf(acc[nt][3] + bs);
      *(ushort4*)(xgB + (rowb + n)*16 + kg*4) = pk;
    }
    return;
  }

  // ---- recurrence role ----
  const int d = blockIdx.x / NSBR;
  const int sbx = blockIdx.x - d*NSBR;
  const int seq0 = sbx * 16;
  const int col = w*16 + lr;

  bf16x8 whf[4][6];
  #pragma unroll
  for (int g = 0; g < 4; g++){
    const unsigned short* wrow = whb + ((size_t)d*768 + g*192 + col)*192;
    #pragma unroll
    for (int kt = 0; kt < 6; kt++)
      whf[g][kt] = *(const bf16x8*)(wrow + kt*32 + kg*8);
  }

  float c_reg[4];
  unsigned short* hsp[4];
  bool val[4];
  const int l0 = d ? (L-1-win0) : win0;
  const ptrdiff_t ldelta = d ? -384 : 384;
  #pragma unroll
  for (int r = 0; r < 4; r++){
    int m = kg*4 + r;
    const float* st = state + (((size_t)d*NSEQ + seq0 + m)*2)*192;
    h_lds[0][m][col] = f2bf(st[col]);
    c_reg[r] = st[192 + col];
    val[r] = (seq0 + m) < nvalid;
    hsp[r] = hs + ((size_t)(seq0+m)*Qrows + (l0+3))*384 + d*192 + col;
  }
  lds_barrier();

  const unsigned short* xq0 = xgA + ((((size_t)d*NSBR + sbx)*TW)*768)*16
                              + ((size_t)col)*16 + kg*4;
  const size_t SSTR = (size_t)768*16;

  uint2 pfA[4], pfB[4];
  {
    const unsigned short* p1 = xq0 + (steps > 1 ? SSTR : 0);
    #pragma unroll
    for (int g = 0; g < 4; g++){
      pfA[g] = *(const uint2*)(xq0 + (size_t)g*(192*16));
      pfB[g] = *(const uint2*)(p1  + (size_t)g*(192*16));
    }
  }

  int cur = 0;
  auto do_step = [&](uint2 (&pf)[4], int ss){
    f32x4 acc[4];
    #pragma unroll
    for (int g = 0; g < 4; g++){
      unsigned int lo = pf[g].x, hi = pf[g].y;
      acc[g][0] = b2f((unsigned short)(lo & 0xffffu));
      acc[g][1] = b2f((unsigned short)(lo >> 16));
      acc[g][2] = b2f((unsigned short)(hi & 0xffffu));
      acc[g][3] = b2f((unsigned short)(hi >> 16));
    }
    int nss = ss + 2; nss = nss > steps-1 ? steps-1 : nss;
    const unsigned short* np = xq0 + (size_t)nss*SSTR;
    #pragma unroll
    for (int g = 0; g < 4; g++)
      pf[g] = *(const uint2*)(np + (size_t)g*(192*16));
    #pragma unroll
    for (int kt = 0; kt < 6; kt++){
      bf16x8 a = *(const bf16x8*)(&h_lds[cur][lr][kt*32 + kg*8]);
      #pragma unroll
      for (int g = 0; g < 4; g++)
        acc[g] = __builtin_amdgcn_mfma_f32_16x16x32_bf16(a, whf[g][kt], acc[g], 0,0,0);
    }
    #pragma unroll
    for (int r = 0; r < 4; r++){
      float gi = sig2(acc[0][r]);
      float gf = sig2(acc[1][r]);
      float gg = tanh2s(acc[2][r]);
      float go = sig2(acc[3][r]);
      float c = gf*c_reg[r] + gi*gg;
      c_reg[r] = c;
      float h = go*tanh_n(c);
      unsigned short hb = f2bf(h);
      h_lds[cur^1][kg*4 + r][col] = hb;
      if (val[r]) __builtin_nontemporal_store(hb, hsp[r]);
      hsp[r] += ldelta;
    }
    lds_barrier();
    cur ^= 1;
  };

  for (int ss = 0; ss < steps; ss += 2){
    do_step(pfA, ss);
    if (ss + 1 < steps) do_step(pfB, ss + 1);
  }

  #pragma unroll
  for (int r = 0; r < 4; r++){
    int m = kg*4 + r;
    float* st = state + (((size_t)d*NSEQ + seq0 + m)*2)*192;
    st[col] = b2f(h_lds[cur][m][col]);
    st[192 + col] = c_reg[r];
  }
}

// ---------------- convT as GEMM: K-split B staging (2 phases, 73.7KB LDS -> 2 blocks/CU) ----------------
template<int MODE>
__global__ __launch_bounds__(512) void gemm_convt(
    const unsigned short* __restrict__ hs, const unsigned short* __restrict__ lwt2,
    const float* __restrict__ lb, const float* __restrict__ addsrc, float* __restrict__ dst)
{
  constexpr int Q  = MODE ? 512 : 65;
  const int lane = threadIdx.x & 63, wave = threadIdx.x >> 6;   // 8 waves
  const int kg = lane >> 4, lr = lane & 15;
  const int R0 = blockIdx.x * 128;

  __shared__ union __align__(16) U {
    unsigned short b[96*48*8];   // 73,728 B
    float c[128][53];
  } sm;

  const int row = R0 + wave*16 + lr;
  const int an = row / Q, aq = row - an*Q;

  f32x4 acc[3] = {};
  #pragma unroll
  for (int p = 0; p < 2; p++){
    if (p) __syncthreads();
    for (int cidx = threadIdx.x; cidx < 4608; cidx += 512)
      *(uint4*)&sm.b[(size_t)cidx*8] = *(const uint4*)(lwt2 + ((size_t)p*4608 + cidx)*8);
    __syncthreads();

    const unsigned short* ab0 = hs + ((size_t)an*(Q+3) + aq + 3 - p*2)*384 + kg*8;
    const unsigned short* ab1 = ab0 - 384;

    bf16x8 pfA = *(const bf16x8*)(ab0);
    bf16x8 pfB = *(const bf16x8*)(ab0 + 32);
    bf16x8 pfC = *(const bf16x8*)(ab0 + 64);
    for (int kt = 0; kt < 24; kt++){
      bf16x8 a = pfA; pfA = pfB; pfB = pfC;
      int nk = kt + 3;
      if (nk < 24)
        pfC = *(const bf16x8*)((nk < 12) ? (ab0 + nk*32) : (ab1 + (nk-12)*32));
      const int bo = (kt*4 + kg)*48*8;
      #pragma unroll
      for (int nt = 0; nt < 3; nt++){
        bf16x8 bfr = *(const bf16x8*)&sm.b[bo + (nt*16 + lr)*8];
        acc[nt] = __builtin_amdgcn_mfma_f32_16x16x32_bf16(a, bfr, acc[nt], 0,0,0);
      }
    }
  }

  if (MODE == 0){
    __syncthreads();
    #pragma unroll
    for (int nt = 0; nt < 3; nt++)
      #pragma unroll
      for (int r = 0; r < 4; r++)
        sm.c[wave*16 + kg*4 + r][nt*16 + lr] = acc[nt][r];
    __syncthreads();
    const int b = R0 >= 33280 ? 1 : 0;
    const size_t bb = (size_t)b*1597440;
    const int rb = R0 - b*33280;
    for (int idx = threadIdx.x; idx < 48*32; idx += 512){
      int n = idx >> 5, g = idx & 31;
      size_t off = bb + (size_t)n*33280 + rb + g*4;
      float4 av = *(const float4*)(addsrc + off);
      float lbn = lb[n];
      float4 o;
      o.x = sm.c[g*4+0][n] + lbn + av.x;
      o.y = sm.c[g*4+1][n] + lbn + av.y;
      o.z = sm.c[g*4+2][n] + lbn + av.z;
      o.w = sm.c[g*4+3][n] + lbn + av.w;
      *(float4*)(dst + off) = o;
    }
  } else {
    #pragma unroll
    for (int nt = 0; nt < 3; nt++){
      int n = nt*16 + lr;
      float lbn = lb[n];
      #pragma unroll
      for (int r = 0; r < 4; r++){
        int orow = R0 + wave*16 + kg*4 + r;
        int ns = orow >> 9, t = orow & 511;
        size_t off = (size_t)(ns/65)*1597440 + (size_t)n*33280 + (ns%65) + (size_t)t*65;
        dst[off] = acc[nt][r] + lbn + addsrc[off];
      }
    }
  }
}

// ---------------- generic row-major bf16 GEMM (BT layout), batched ----------------
__global__ __launch_bounds__(256) void gemm_rm(
    const unsigned short* __restrict__ A, const unsigned short* __restrict__ B, float* __restrict__ C,
    int lda, int ldb, int ldc, int KT, int nmax, long long strA, long long strB, long long strC)
{
  const int z = blockIdx.z;
  A += (size_t)z * strA; B += (size_t)z * strB; C += (size_t)z * strC;
  const int lane = threadIdx.x & 63, wave = threadIdx.x >> 6;
  const int kg = lane >> 4, lr = lane & 15;
  const int rowbase = blockIdx.x*128 + wave*32;
  const int nbase = blockIdx.y*64;
  f32x4 acc[2][4] = {};
  for (int kt = 0; kt < KT; kt++){
    int k0 = kt*32 + kg*8;
    bf16x8 a0 = *(const bf16x8*)(A + (size_t)(rowbase+lr)*lda + k0);
    bf16x8 a1 = *(const bf16x8*)(A + (size_t)(rowbase+16+lr)*lda + k0);
    #pragma unroll
    for (int nt = 0; nt < 4; nt++){
      bf16x8 bfr = *(const bf16x8*)(B + (size_t)(nbase+nt*16+lr)*ldb + k0);
      acc[0][nt] = __builtin_amdgcn_mfma_f32_16x16x32_bf16(a0, bfr, acc[0][nt], 0,0,0);
      acc[1][nt] = __builtin_amdgcn_mfma_f32_16x16x32_bf16(a1, bfr, acc[1][nt], 0,0,0);
    }
  }
  #pragma unroll
  for (int mt = 0; mt < 2; mt++)
  #pragma unroll
  for (int nt = 0; nt < 4; nt++)
  #pragma unroll
  for (int r = 0; r < 4; r++){
    int n = nbase + nt*16 + lr;
    if (n < nmax){
      int row = rowbase + mt*16 + kg*4 + r;
      C[(size_t)row*ldc + n] = acc[mt][nt][r];
    }
  }
}

// ---------------- FUSED qkv projection + prelu + LN over (e,f): float4 LDS, padded rows ----------------
// in_t [65][52]: pad 48->52 so bank-quad = (13f + c4) mod 8 sweeps all 8 -> conflict-free b128.
__global__ __launch_bounds__(256) void qkv3_k(
    const float* __restrict__ inter,
    const float* __restrict__ qw, const float* __restrict__ qb, const float* __restrict__ qa,
    const float* __restrict__ qg, const float* __restrict__ qbe,
    const float* __restrict__ kw, const float* __restrict__ kb, const float* __restrict__ ka,
    const float* __restrict__ kgm, const float* __restrict__ kbe,
    const float* __restrict__ vw, const float* __restrict__ vb, const float* __restrict__ va,
    const float* __restrict__ vg, const float* __restrict__ vbe,
    unsigned short* __restrict__ q2b, unsigned short* __restrict__ k2b,
    unsigned short* __restrict__ v2t)
{
  int t = blockIdx.x; int hb = blockIdx.y; int h = hb >> 1, b = hb & 1;
  __shared__ __align__(16) float in_t[65][52];
  __shared__ __align__(16) float w_l[28][48];
  __shared__ float y_l[780];
  __shared__ float rs1[4], rs2[4];
  const float* base = inter + (size_t)b*(48*512*65) + (size_t)t*65;
  for (int i = threadIdx.x; i < 48*65; i += 256){
    int c = i/65, q = i - c*65;
    in_t[q][c] = base[(size_t)c*(512*65) + q];
  }
  for (int i = threadIdx.x; i < 8*48; i += 256)  w_l[i/48][i%48]      = qw[(size_t)h*8*48 + i];
  for (int i = threadIdx.x; i < 8*48; i += 256)  w_l[8 + i/48][i%48]  = kw[(size_t)h*8*48 + i];
  for (int i = threadIdx.x; i < 12*48; i += 256) w_l[16 + i/48][i%48] = vw[(size_t)h*12*48 + i];
  __syncthreads();

  #pragma unroll
  for (int ph = 0; ph < 3; ph++){
    const int E   = (ph == 2) ? 12 : 8;
    const int wo  = (ph == 0) ? 0 : (ph == 1 ? 8 : 16);
    const float* bias  = (ph == 0) ? qb  : (ph == 1 ? kb  : vb);
    const float* alpha = (ph == 0) ? qa  : (ph == 1 ? ka  : va);
    const float* gam   = (ph == 0) ? qg  : (ph == 1 ? kgm : vg);
    const float* bet   = (ph == 0) ? qbe : (ph == 1 ? kbe : vbe);
    int nel = E*65;
    float a = alpha[h];
    float ps = 0.f, pq = 0.f;
    for (int i = threadIdx.x; i < nel; i += 256){
      int e = i/65, f = i - e*65;
      float s = bias[h*E + e];
      const float4* wr = (const float4*)&w_l[wo + e][0];
      const float4* xr = (const float4*)&in_t[f][0];
      #pragma unroll
      for (int c4 = 0; c4 < 12; c4++){
        float4 wv = wr[c4], xv = xr[c4];
        s += wv.x*xv.x + wv.y*xv.y + wv.z*xv.z + wv.w*xv.w;
      }
      s = s >= 0.f ? s : a*s;
      y_l[i] = s; ps += s; pq += s*s;
    }
    #pragma unroll
    for (int o = 32; o; o >>= 1){ ps += __shfl_xor(ps, o); pq += __shfl_xor(pq, o); }
    if ((threadIdx.x & 63) == 0){ rs1[threadIdx.x>>6] = ps; rs2[threadIdx.x>>6] = pq; }
    __syncthreads();
    ps = rs1[0]+rs1[1]+rs1[2]+rs1[3]; pq = rs2[0]+rs2[1]+rs2[2]+rs2[3];
    float inv = 1.0f/(float)nel;
    float m = ps*inv; float rstd = rsqrtf(pq*inv - m*m + 1e-5f);
    for (int i = threadIdx.x; i < nel; i += 256){
      int e = i/65, f = i - e*65;
      float v = (y_l[i]-m)*rstd*gam[(size_t)(h*E+e)*65 + f] + bet[(size_t)(h*E+e)*65 + f];
      if (ph == 0)      q2b[((size_t)hb*512 + t)*544 + i] = f2bf(v);
      else if (ph == 1) k2b[((size_t)hb*512 + t)*544 + i] = f2bf(v);
      else              v2t[((size_t)hb*832 + i)*512 + t] = f2bf(v);
    }
    __syncthreads();
  }
}

// ---------------- softmax over rows of 512 ----------------
__global__ __launch_bounds__(256) void softmax_k(const float* __restrict__ S, unsigned short* __restrict__ P){
  size_t row = (size_t)blockIdx.y*512 + blockIdx.x;
  const float* s = S + row*512;
  int tid = threadIdx.x;
  float v0 = s[tid], v1 = s[tid+256];
  float m = fmaxf(v0, v1);
  #pragma unroll
  for (int o = 32; o; o >>= 1) m = fmaxf(m, __shfl_xor(m, o));
  __shared__ float r4[4], q4[4];
  if ((tid & 63) == 0) r4[tid>>6] = m;
  __syncthreads();
  m = fmaxf(fmaxf(r4[0], r4[1]), fmaxf(r4[2], r4[3]));
  const float sc = 0.04385290096535146f;  // 1/sqrt(520)
  float e0 = __expf((v0-m)*sc), e1 = __expf((v1-m)*sc);
  float su = e0 + e1;
  #pragma unroll
  for (int o = 32; o; o >>= 1) su += __shfl_xor(su, o);
  if ((tid & 63) == 0) q4[tid>>6] = su;
  __syncthreads();
  su = q4[0]+q4[1]+q4[2]+q4[3];
  float inv = __builtin_amdgcn_rcpf(su);
  unsigned short* p = P + row*512;
  p[tid] = f2bf(e0*inv); p[tid+256] = f2bf(e1*inv);
}

// ---------------- final projection + prelu + LN over (c,f) + residual ----------------
__global__ __launch_bounds__(256) void pout_k(
    const float* __restrict__ o, const float* __restrict__ pw, const float* __restrict__ pb,
    const float* __restrict__ pa, const float* __restrict__ pg, const float* __restrict__ pbe,
    const float* __restrict__ inter, float* __restrict__ out)
{
  int bt = blockIdx.x; int b = bt >> 9, t = bt & 511;
  __shared__ float o_l[48][66];
  __shared__ float pw_l[48][48];
  __shared__ float p_l[3120];
  __shared__ float rs1[4], rs2[4];
  for (int i = threadIdx.x; i < 48*65; i += 256){
    int c = i/65, f = i - c*65; int h = c/12, dd = c - h*12;
    o_l[c][f] = o[((size_t)(h*2+b)*512 + t)*780 + dd*65 + f];
  }
  for (int i = threadIdx.x; i < 48*48; i += 256) pw_l[i/48][i - (i/48)*48] = pw[i];
  __syncthreads();
  float a = pa[0];
  float ps = 0.f, pq = 0.f;
  for (int i = threadIdx.x; i < 3120; i += 256){
    int oc = i/65, f = i - oc*65;
    float s = pb[oc];
    #pragma unroll
    for (int c = 0; c < 48; c++) s += pw_l[oc][c]*o_l[c][f];
    s = s >= 0.f ? s : a*s;
    p_l[i] = s; ps += s; pq += s*s;
  }
  #pragma unroll
  for (int o2 = 32; o2; o2 >>= 1){ ps += __shfl_xor(ps, o2); pq += __shfl_xor(pq, o2); }
  if ((threadIdx.x & 63) == 0){ rs1[threadIdx.x>>6] = ps; rs2[threadIdx.x>>6] = pq; }
  __syncthreads();
  ps = rs1[0]+rs1[1]+rs1[2]+rs1[3]; pq = rs2[0]+rs2[1]+rs2[2]+rs2[3];
  float m = ps*(1.0f/3120.0f); float rstd = rsqrtf(pq*(1.0f/3120.0f) - m*m + 1e-5f);
  for (int i = threadIdx.x; i < 3120; i += 256){
    int oc = i/65, f = i - oc*65;
    size_t off = ((size_t)(b*48+oc)*512 + t)*65 + f;
    out[off] = (p_l[i]-m)*rstd*pg[i] + pbe[i] + inter[off];
  }
}

// ---------------- launch ----------------

extern "C" void kernel_launch(void* const* d_in, const int* in_sizes, int n_in,
                              void* d_out, int out_size, void* d_ws, size_t ws_size,
                              hipStream_t stream)
{
  const float* x         = (const float*)d_in[0];
  const float* intra_g   = (const float*)d_in[2];
  const float* intra_b   = (const float*)d_in[3];
  const float* intra_wih = (const float*)d_in[4];
  const float* intra_whh = (const float*)d_in[5];
  const float* intra_bih = (const float*)d_in[6];
  const float* intra_bhh = (const float*)d_in[7];
  const float* intra_lw  = (const float*)d_in[8];
  const float* intra_lb  = (const float*)d_in[9];
  const float* inter_g   = (const float*)d_in[10];
  const float* inter_b   = (const float*)d_in[11];
  const float* inter_wih = (const float*)d_in[12];
  const float* inter_whh = (const float*)d_in[13];
  const float* inter_bih = (const float*)d_in[14];
  const float* inter_bhh = (const float*)d_in[15];
  const float* inter_lw  = (const float*)d_in[16];
  const float* inter_lb  = (const float*)d_in[17];
  const float* qw  = (const float*)d_in[18];
  const float* qb  = (const float*)d_in[19];
  const float* qa  = (const float*)d_in[20];
  const float* qg  = (const float*)d_in[21];
  const float* qbe = (const float*)d_in[22];
  const float* kw  = (const float*)d_in[23];
  const float* kb  = (const float*)d_in[24];
  const float* ka  = (const float*)d_in[25];
  const float* kgm = (const float*)d_in[26];
  const float* kbe = (const float*)d_in[27];
  const float* vw  = (const float*)d_in[28];
  const float* vb  = (const float*)d_in[29];
  const float* va  = (const float*)d_in[30];
  const float* vg  = (const float*)d_in[31];
  const float* vbe = (const float*)d_in[32];
  const float* pw  = (const float*)d_in[33];
  const float* pb  = (const float*)d_in[34];
  const float* pa  = (const float*)d_in[35];
  const float* pgm = (const float*)d_in[36];
  const float* pbe = (const float*)d_in[37];

  char* ws = (char*)d_ws;
  constexpr size_t WIB_INTRA = 0;
  constexpr size_t WHB_INTRA = 589824;
  constexpr size_t WIB_INTER = 1179648;
  constexpr size_t WHB_INTER = 1769472;
  constexpr size_t LWT_INTRA = 2359296;
  constexpr size_t LWT_INTER = 2555904;
  constexpr size_t BIAS_INTRA = 2752512;
  constexpr size_t BIAS_INTER = 2758656;
  constexpr size_t UNF   = 2764800;
  constexpr size_t INTER = 2764800;            // alias: written only after UNF is dead
  constexpr size_t STATE = 28311552;
  constexpr size_t HS    = 31457280;
  constexpr size_t INTRA = 84934656;
  constexpr size_t XG    = 97714176;           // double-buffered region (50,331,648 B)
  constexpr size_t Q2B   = XG;
  constexpr size_t K2B   = XG + 4456448;
  constexpr size_t V2T   = XG + 8912896;
  constexpr size_t SCORES= XG + 15728640;
  constexpr size_t ATTNB = XG + 24117248;
  constexpr size_t OBUF  = XG + 28311552;

  auto U16 = [&](size_t off){ return (unsigned short*)(ws + off); };
  auto F32 = [&](size_t off){ return (float*)(ws + off); };

  // ---- prep (single dispatch) ----
  prep_all<<<5197,256,0,stream>>>(intra_wih, intra_whh, inter_wih, inter_whh,
                                  intra_bih, intra_bhh, inter_bih, inter_bhh,
                                  intra_lw, inter_lw,
                                  U16(WIB_INTRA), U16(WHB_INTRA), U16(WIB_INTER), U16(WHB_INTER),
                                  F32(BIAS_INTRA), F32(BIAS_INTER),
                                  U16(LWT_INTRA), U16(LWT_INTER));

  // ---- intra stage (TW=8, 8 windows, xg fused with rec) ----
  {
    unsigned short* xb[2] = { U16(XG), U16(XG + 25165824) };
    ln_unf_intra<<<1024,256,0,stream>>>(x, intra_g, intra_b, U16(UNF));
    zero_stage<<<9984,256,0,stream>>>(U16(HS), 1024, 68, 62, (uint4*)(ws+STATE));
    gemm_xg<<<dim3(64,12,2),256,0,stream>>>(U16(UNF), U16(WIB_INTRA), F32(BIAS_INTRA), xb[0],
                                            1024, 8, 0, 62, 1024);
    for (int w = 0; w < 8; w++){
      int win0 = w*8;
      int steps = (62 - win0) < 8 ? (62 - win0) : 8;
      int nxg = (w < 7) ? 1536 : 0;   // 2 dirs x 64 sb x 1 slb x 12 nb
      fused_rec_xg<<<128 + nxg, 768, 0, stream>>>(
          xb[w&1], U16(WHB_INTRA), U16(HS), F32(STATE),
          U16(UNF), U16(WIB_INTRA), F32(BIAS_INTRA), xb[(w+1)&1],
          1024, 8, win0, 62, 68, 1024, steps,
          128, 64, 1, (w+1)*8);
    }
    gemm_convt<0><<<520,512,0,stream>>>(U16(HS), U16(LWT_INTRA), intra_lb, x, F32(INTRA));
  }

  // ---- inter stage (TW=48, 11 windows, xg fused with rec) ----
  {
    unsigned short* xb[2] = { U16(XG), U16(XG + 21233664) };
    ln_unf_inter<<<1024,256,0,stream>>>(F32(INTRA), inter_g, inter_b, U16(UNF));
    zero_stage<<<1938,256,0,stream>>>(U16(HS), 130, 515, 509, (uint4*)(ws+STATE));
    gemm_xg<<<dim3(54,12,2),256,0,stream>>>(U16(UNF), U16(WIB_INTER), F32(BIAS_INTER), xb[0],
                                            144, 48, 0, 509, 130);
    for (int w = 0; w < 11; w++){
      int win0 = w*48;
      int steps = (509 - win0) < 48 ? (509 - win0) : 48;
      int nxg = (w < 10) ? 864 : 0;   // 2 dirs x 9 sb x 4 slb x 12 nb
      fused_rec_xg<<<18 + nxg, 768, 0, stream>>>(
          xb[w&1], U16(WHB_INTER), U16(HS), F32(STATE),
          U16(UNF), U16(WIB_INTER), F32(BIAS_INTER), xb[(w+1)&1],
          144, 48, win0, 509, 515, 130, steps,
          18, 9, 4, (w+1)*48);
    }
    gemm_convt<1><<<520,512,0,stream>>>(U16(HS), U16(LWT_INTER), inter_lb, F32(INTRA), F32(INTER));
  }

  // ---- attention stage ----
  zero16<<<2048,256,0,stream>>>((uint4*)(ws+Q2B), 15728640/16);
  qkv3_k<<<dim3(512,8),256,0,stream>>>(F32(INTER),
                                       qw, qb, qa, qg, qbe,
                                       kw, kb, ka, kgm, kbe,
                                       vw, vb, va, vg, vbe,
                                       U16(Q2B), U16(K2B), U16(V2T));
  gemm_rm<<<dim3(4,8,8),256,0,stream>>>(U16(Q2B), U16(K2B), F32(SCORES),
                                        544, 544, 512, 17, 512,
                                        (long long)512*544, (long long)512*544, (long long)512*512);
  softmax_k<<<dim3(512,8),256,0,stream>>>(F32(SCORES), U16(ATTNB));
  gemm_rm<<<dim3(4,13,8),256,0,stream>>>(U16(ATTNB), U16(V2T), F32(OBUF),
                                         512, 512, 780, 16, 780,
                                         (long long)512*512, (long long)832*512, (long long)512*780);
  pout_k<<<1024,256,0,stream>>>(F32(OBUF), pw, pb, pa, pgm, pbe, F32(INTER), (float*)d_out);
}

// Round 15
// 1597.569 us; speedup vs baseline: 1.0178x; 1.0038x over previous
//
#include <hip/hip_runtime.h>
#include <hip/hip_bf16.h>

typedef __bf16 bf16x8 __attribute__((ext_vector_type(8)));
typedef unsigned short u16x8 __attribute__((ext_vector_type(8)));
typedef float f32x4 __attribute__((ext_vector_type(4)));

#define DEV static __device__ __forceinline__

DEV unsigned short f2bf(float f){
  __hip_bfloat16 h = __float2bfloat16(f);
  return __builtin_bit_cast(unsigned short, h);
}
DEV float b2f(unsigned short u){
  return __bfloat162float(__builtin_bit_cast(__hip_bfloat16, u));
}
// gate math in exp2 domain: inputs pre-scaled by log2(e)
DEV float sig2(float xs){
  return __builtin_amdgcn_rcpf(1.0f + __builtin_amdgcn_exp2f(-xs));
}
DEV float tanh2s(float xs){
  return 1.0f - 2.0f*__builtin_amdgcn_rcpf(__builtin_amdgcn_exp2f(xs + xs) + 1.0f);
}
DEV float tanh_n(float x){
  return 1.0f - 2.0f*__builtin_amdgcn_rcpf(__builtin_amdgcn_exp2f(x * 2.885390082f) + 1.0f);
}
DEV void lds_barrier(){
  asm volatile("s_waitcnt lgkmcnt(0)\ns_barrier" ::: "memory");
}

// ---------------- utility kernels ----------------

__global__ void zero16(uint4* p, size_t n){
  size_t i = (size_t)blockIdx.x*blockDim.x + threadIdx.x;
  size_t st = (size_t)gridDim.x*blockDim.x;
  uint4 z = make_uint4(0u,0u,0u,0u);
  for (; i < n; i += st) p[i] = z;
}

// combined: zero hs conv-pad rows + STATE buffer (one dispatch per stage)
__global__ void zero_stage(unsigned short* hs, int NSEQ, int Qrows, int L, uint4* state){
  int i = blockIdx.x*256 + threadIdx.x;
  int padsN = NSEQ*6*384;
  if (i < padsN){
    int t = i/(6*384); int rem = i - t*(6*384);
    int r = rem/384, c = rem - r*384;
    int row = r < 3 ? r : L + r;
    hs[((size_t)t*Qrows + row)*384 + c] = 0;
  } else {
    int j = i - padsN;
    if (j < 196608) state[j] = make_uint4(0u,0u,0u,0u);
  }
}

// ---------------- fused prep: weight casts (log2e-scaled), bias combine, lwt build ----------------
__global__ void prep_all(
    const float* __restrict__ intra_wih, const float* __restrict__ intra_whh,
    const float* __restrict__ inter_wih, const float* __restrict__ inter_whh,
    const float* __restrict__ intra_bih, const float* __restrict__ intra_bhh,
    const float* __restrict__ inter_bih, const float* __restrict__ inter_bhh,
    const float* __restrict__ intra_lw,  const float* __restrict__ inter_lw,
    unsigned short* __restrict__ wib_a, unsigned short* __restrict__ whb_a,
    unsigned short* __restrict__ wib_e, unsigned short* __restrict__ whb_e,
    float* __restrict__ bias_a, float* __restrict__ bias_e,
    unsigned short* __restrict__ lwt_a, unsigned short* __restrict__ lwt_e)
{
  const float LOG2E = 1.4426950408889634f;
  int i = blockIdx.x*256 + threadIdx.x;
  if (i < 294912){
    int dn = i/192, k = i - dn*192;
    int c = k >> 2, kk = k & 3;
    wib_a[(size_t)dn*192 + kk*48 + c] = f2bf(intra_wih[i]*LOG2E);
  } else if (i < 589824){
    int j = i - 294912;
    whb_a[j] = f2bf(intra_whh[j]*LOG2E);
  } else if (i < 884736){
    int j = i - 589824;
    int dn = j/192, k = j - dn*192;
    int c = k >> 2, kk = k & 3;
    wib_e[(size_t)dn*192 + kk*48 + c] = f2bf(inter_wih[j]*LOG2E);
  } else if (i < 1179648){
    int j = i - 884736;
    whb_e[j] = f2bf(inter_whh[j]*LOG2E);
  } else if (i < 1181184){
    int j = i - 1179648;
    bias_a[j] = (intra_bih[j] + intra_bhh[j])*LOG2E;
  } else if (i < 1182720){
    int j = i - 1181184;
    bias_e[j] = (inter_bih[j] + inter_bhh[j])*LOG2E;
  } else if (i < 1256448){
    int j = i - 1182720;
    int m = j / 192; int rest = j - m*192; int c = rest >> 2; int k = rest & 3;
    int kap = k*384 + m;
    lwt_a[((size_t)(kap>>3)*48 + c)*8 + (kap&7)] = f2bf(intra_lw[j]);
  } else if (i < 1330176){
    int j = i - 1256448;
    int m = j / 192; int rest = j - m*192; int c = rest >> 2; int k = rest & 3;
    int kap = k*384 + m;
    lwt_e[((size_t)(kap>>3)*48 + c)*8 + (kap&7)] = f2bf(inter_lw[j]);
  }
}

// ---------------- LN over C + unfold -> bf16 unf[seq][l][kk*48+c] ----------------
__global__ __launch_bounds__(256) void ln_unf_intra(
    const float* __restrict__ in, const float* __restrict__ g,
    const float* __restrict__ be, unsigned short* __restrict__ unf)
{
  int bt = blockIdx.x; int b = bt >> 9, t = bt & 511;
  __shared__ float v[48][66];
  __shared__ float mu[65], rs[65];
  __shared__ float g_l[48], b_l[48];
  const float* base = in + (size_t)b*(48*512*65) + (size_t)t*65;
  for (int i = threadIdx.x; i < 48*65; i += 256){
    int c = i/65, q = i - c*65;
    v[c][q] = base[(size_t)c*(512*65) + q];
  }
  if (threadIdx.x < 48){ g_l[threadIdx.x] = g[threadIdx.x]; b_l[threadIdx.x] = be[threadIdx.x]; }
  __syncthreads();
  if (threadIdx.x < 65){
    int q = threadIdx.x; float s=0.f, s2=0.f;
    #pragma unroll
    for (int c = 0; c < 48; c++){ float x = v[c][q]; s += x; s2 += x*x; }
    float m = s*(1.0f/48.0f);
    mu[q] = m; rs[q] = rsqrtf(s2*(1.0f/48.0f) - m*m + 1e-5f);
  }
  __syncthreads();
  unsigned short* orow = unf + (size_t)(b*512 + t)*62*192;
  for (int idx = threadIdx.x; idx < 62*24; idx += 256){
    int l = idx/24, jg = idx - l*24;
    int kk = jg/6, c0 = (jg - kk*6)*8;
    int q = l + kk;
    ushort4 p0, p1;
    float mq = mu[q], rq = rs[q];
    p0.x = f2bf((v[c0+0][q]-mq)*rq*g_l[c0+0] + b_l[c0+0]);
    p0.y = f2bf((v[c0+1][q]-mq)*rq*g_l[c0+1] + b_l[c0+1]);
    p0.z = f2bf((v[c0+2][q]-mq)*rq*g_l[c0+2] + b_l[c0+2]);
    p0.w = f2bf((v[c0+3][q]-mq)*rq*g_l[c0+3] + b_l[c0+3]);
    p1.x = f2bf((v[c0+4][q]-mq)*rq*g_l[c0+4] + b_l[c0+4]);
    p1.y = f2bf((v[c0+5][q]-mq)*rq*g_l[c0+5] + b_l[c0+5]);
    p1.z = f2bf((v[c0+6][q]-mq)*rq*g_l[c0+6] + b_l[c0+6]);
    p1.w = f2bf((v[c0+7][q]-mq)*rq*g_l[c0+7] + b_l[c0+7]);
    *(ushort4*)(orow + (size_t)l*192 + kk*48 + c0) = p0;
    *(ushort4*)(orow + (size_t)l*192 + kk*48 + c0 + 4) = p1;
  }
}

__global__ __launch_bounds__(256) void ln_unf_inter(
    const float* __restrict__ in, const float* __restrict__ g,
    const float* __restrict__ be, unsigned short* __restrict__ unf)
{
  int bt = blockIdx.x; int b = bt >> 9, t = bt & 511;
  __shared__ float v[48][66];
  __shared__ float mu[65], rs[65];
  __shared__ float g_l[48], b_l[48];
  const float* base = in + (size_t)b*(48*512*65) + (size_t)t*65;
  for (int i = threadIdx.x; i < 48*65; i += 256){
    int c = i/65, q = i - c*65;
    v[c][q] = base[(size_t)c*(512*65) + q];
  }
  if (threadIdx.x < 48){ g_l[threadIdx.x] = g[threadIdx.x]; b_l[threadIdx.x] = be[threadIdx.x]; }
  __syncthreads();
  if (threadIdx.x < 65){
    int q = threadIdx.x; float s=0.f, s2=0.f;
    #pragma unroll
    for (int c = 0; c < 48; c++){ float x = v[c][q]; s += x; s2 += x*x; }
    float m = s*(1.0f/48.0f);
    mu[q] = m; rs[q] = rsqrtf(s2*(1.0f/48.0f) - m*m + 1e-5f);
  }
  __syncthreads();
  for (int idx = threadIdx.x; idx < 4*65*6; idx += 256){
    int s = idx/390;
    int rem = idx - s*390;
    int q = rem/6, c0 = (rem - q*6)*8;
    int l = t - 3 + s, kk = 3 - s;
    if (l < 0 || l > 508) continue;
    float mq = mu[q], rq = rs[q];
    ushort4 p0, p1;
    p0.x = f2bf((v[c0+0][q]-mq)*rq*g_l[c0+0] + b_l[c0+0]);
    p0.y = f2bf((v[c0+1][q]-mq)*rq*g_l[c0+1] + b_l[c0+1]);
    p0.z = f2bf((v[c0+2][q]-mq)*rq*g_l[c0+2] + b_l[c0+2]);
    p0.w = f2bf((v[c0+3][q]-mq)*rq*g_l[c0+3] + b_l[c0+3]);
    p1.x = f2bf((v[c0+4][q]-mq)*rq*g_l[c0+4] + b_l[c0+4]);
    p1.y = f2bf((v[c0+5][q]-mq)*rq*g_l[c0+5] + b_l[c0+5]);
    p1.z = f2bf((v[c0+6][q]-mq)*rq*g_l[c0+6] + b_l[c0+6]);
    p1.w = f2bf((v[c0+7][q]-mq)*rq*g_l[c0+7] + b_l[c0+7]);
    size_t addr = ((size_t)(b*65+q)*509 + l)*192 + kk*48 + c0;
    *(ushort4*)(unf + addr) = p0;
    *(ushort4*)(unf + addr + 4) = p1;
  }
}

// ---------------- GEMM: xg = unf @ Wi^T + bias (standalone, prologue window) ----------------
__global__ __launch_bounds__(256) void gemm_xg(
    const unsigned short* __restrict__ unf, const unsigned short* __restrict__ wib,
    const float* __restrict__ bias, unsigned short* __restrict__ xg,
    int NSEQ, int TW, int win0, int L, int nvalid)
{
  const int d = blockIdx.z;
  const int lane = threadIdx.x & 63, wave = threadIdx.x >> 6;
  const int kg = lane >> 4, lr = lane & 15;
  const int nslb = TW >> 3;
  const int sb  = blockIdx.x / nslb;
  const int slb = blockIdx.x - sb*nslb;
  const int nbase = blockIdx.y*64;
  const unsigned short* Bp = wib + (size_t)d*768*192;

  const unsigned short* abase[2];
  #pragma unroll
  for (int mt = 0; mt < 2; mt++){
    int sl = slb*8 + wave*2 + mt;
    int s = win0 + sl;
    int l = d ? (L-1-s) : s;
    l = l < 0 ? 0 : (l > L-1 ? L-1 : l);
    int seq = sb*16 + lr;
    seq = seq < nvalid ? seq : nvalid-1;
    abase[mt] = unf + ((size_t)seq*L + l)*192;
  }

  f32x4 acc[2][4] = {};
  #pragma unroll
  for (int kt = 0; kt < 6; kt++){
    int k0 = kt*32 + kg*8;
    bf16x8 a0 = *(const bf16x8*)(abase[0] + k0);
    bf16x8 a1 = *(const bf16x8*)(abase[1] + k0);
    #pragma unroll
    for (int nt = 0; nt < 4; nt++){
      int n = nbase + nt*16 + lr;
      bf16x8 bfr = *(const bf16x8*)(Bp + (size_t)n*192 + k0);
      acc[0][nt] = __builtin_amdgcn_mfma_f32_16x16x32_bf16(a0, bfr, acc[0][nt], 0,0,0);
      acc[1][nt] = __builtin_amdgcn_mfma_f32_16x16x32_bf16(a1, bfr, acc[1][nt], 0,0,0);
    }
  }
  #pragma unroll
  for (int mt = 0; mt < 2; mt++){
    int sl = slb*8 + wave*2 + mt;
    size_t rowb = (((size_t)d*(NSEQ>>4) + sb)*TW + sl)*768;
    #pragma unroll
    for (int nt = 0; nt < 4; nt++){
      int n = nbase + nt*16 + lr;
      float bs = bias[d*768 + n];
      ushort4 pk;
      pk.x = f2bf(acc[mt][nt][0] + bs);
      pk.y = f2bf(acc[mt][nt][1] + bs);
      pk.z = f2bf(acc[mt][nt][2] + bs);
      pk.w = f2bf(acc[mt][nt][3] + bs);
      *(ushort4*)(xg + (rowb + n)*16 + kg*4) = pk;
    }
  }
}

// ---------------- FUSED: recurrence(window w) + xg GEMM(window w+1) ----------------
__global__ __launch_bounds__(768, 3) void fused_rec_xg(
    const unsigned short* __restrict__ xgA,  // [2][NSBR][TW][768][16]
    const unsigned short* __restrict__ whb,  // [2][768][192]
    unsigned short* __restrict__ hs,         // [NSEQ][Qrows][384]
    float* __restrict__ state,               // [2][NSEQ][2][192]
    const unsigned short* __restrict__ unf,
    const unsigned short* __restrict__ wib,
    const float* __restrict__ bias,
    unsigned short* __restrict__ xgB,
    int NSEQ, int TW, int win0, int L, int Qrows, int nvalid, int steps,
    int NR, int NSBR, int NSLB, int win0x)
{
  const int tid = threadIdx.x;
  const int lane = tid & 63, w = tid >> 6;
  const int kg = lane >> 4, lr = lane & 15;

  __shared__ unsigned short h_lds[2][16][200];

  if ((int)blockIdx.x >= NR){
    // ---- xg role ----
    int e = blockIdx.x - NR;
    int nb = e % 12; e /= 12;
    int slb = e % NSLB; e /= NSLB;
    int sb = e % NSBR; int d = e / NSBR;
    int sl = slb*12 + w;
    if (sl >= TW) return;
    int s = win0x + sl;
    int l = d ? (L-1-s) : s;
    l = l < 0 ? 0 : (l > L-1 ? L-1 : l);
    int seq = sb*16 + lr;
    seq = seq < nvalid ? seq : nvalid-1;
    const unsigned short* ab = unf + ((size_t)seq*L + l)*192;
    const unsigned short* Bp = wib + (size_t)d*768*192;
    const int nbase = nb*64;
    f32x4 acc[4] = {};
    #pragma unroll
    for (int kt = 0; kt < 6; kt++){
      int k0 = kt*32 + kg*8;
      bf16x8 a = *(const bf16x8*)(ab + k0);
      #pragma unroll
      for (int nt = 0; nt < 4; nt++){
        bf16x8 bfr = *(const bf16x8*)(Bp + (size_t)(nbase+nt*16+lr)*192 + k0);
        acc[nt] = __builtin_amdgcn_mfma_f32_16x16x32_bf16(a, bfr, acc[nt], 0,0,0);
      }
    }
    size_t rowb = (((size_t)d*NSBR + sb)*TW + sl)*768;
    #pragma unroll
    for (int nt = 0; nt < 4; nt++){
      int n = nbase + nt*16 + lr;
      float bs = bias[d*768 + n];
      ushort4 pk;
      pk.x = f2bf(acc[nt][0] + bs);
      pk.y = f2bf(acc[nt][1] + bs);
      pk.z = f2bf(acc[nt][2] + bs);
      pk.w = f2bf(acc[nt][3] + bs);
      *(ushort4*)(xgB + (rowb + n)*16 + kg*4) = pk;
    }
    return;
  }

  // ---- recurrence role ----
  const int d = blockIdx.x / NSBR;
  const int sbx = blockIdx.x - d*NSBR;
  const int seq0 = sbx * 16;
  const int col = w*16 + lr;

  bf16x8 whf[4][6];
  #pragma unroll
  for (int g = 0; g < 4; g++){
    const unsigned short* wrow = whb + ((size_t)d*768 + g*192 + col)*192;
    #pragma unroll
    for (int kt = 0; kt < 6; kt++)
      whf[g][kt] = *(const bf16x8*)(wrow + kt*32 + kg*8);
  }

  float c_reg[4];
  unsigned short* hsp[4];
  bool val[4];
  const int l0 = d ? (L-1-win0) : win0;
  const ptrdiff_t ldelta = d ? -384 : 384;
  #pragma unroll
  for (int r = 0; r < 4; r++){
    int m = kg*4 + r;
    const float* st = state + (((size_t)d*NSEQ + seq0 + m)*2)*192;
    h_lds[0][m][col] = f2bf(st[col]);
    c_reg[r] = st[192 + col];
    val[r] = (seq0 + m) < nvalid;
    hsp[r] = hs + ((size_t)(seq0+m)*Qrows + (l0+3))*384 + d*192 + col;
  }
  lds_barrier();

  const unsigned short* xq0 = xgA + ((((size_t)d*NSBR + sbx)*TW)*768)*16
                              + ((size_t)col)*16 + kg*4;
  const size_t SSTR = (size_t)768*16;

  uint2 pfA[4], pfB[4];
  {
    const unsigned short* p1 = xq0 + (steps > 1 ? SSTR : 0);
    #pragma unroll
    for (int g = 0; g < 4; g++){
      pfA[g] = *(const uint2*)(xq0 + (size_t)g*(192*16));
      pfB[g] = *(const uint2*)(p1  + (size_t)g*(192*16));
    }
  }

  int cur = 0;
  auto do_step = [&](uint2 (&pf)[4], int ss){
    f32x4 acc[4];
    #pragma unroll
    for (int g = 0; g < 4; g++){
      unsigned int lo = pf[g].x, hi = pf[g].y;
      acc[g][0] = b2f((unsigned short)(lo & 0xffffu));
      acc[g][1] = b2f((unsigned short)(lo >> 16));
      acc[g][2] = b2f((unsigned short)(hi & 0xffffu));
      acc[g][3] = b2f((unsigned short)(hi >> 16));
    }
    int nss = ss + 2; nss = nss > steps-1 ? steps-1 : nss;
    const unsigned short* np = xq0 + (size_t)nss*SSTR;
    #pragma unroll
    for (int g = 0; g < 4; g++)
      pf[g] = *(const uint2*)(np + (size_t)g*(192*16));
    #pragma unroll
    for (int kt = 0; kt < 6; kt++){
      bf16x8 a = *(const bf16x8*)(&h_lds[cur][lr][kt*32 + kg*8]);
      #pragma unroll
      for (int g = 0; g < 4; g++)
        acc[g] = __builtin_amdgcn_mfma_f32_16x16x32_bf16(a, whf[g][kt], acc[g], 0,0,0);
    }
    #pragma unroll
    for (int r = 0; r < 4; r++){
      float gi = sig2(acc[0][r]);
      float gf = sig2(acc[1][r]);
      float gg = tanh2s(acc[2][r]);
      float go = sig2(acc[3][r]);
      float c = gf*c_reg[r] + gi*gg;
      c_reg[r] = c;
      float h = go*tanh_n(c);
      unsigned short hb = f2bf(h);
      h_lds[cur^1][kg*4 + r][col] = hb;
      if (val[r]) __builtin_nontemporal_store(hb, hsp[r]);
      hsp[r] += ldelta;
    }
    lds_barrier();
    cur ^= 1;
  };

  for (int ss = 0; ss < steps; ss += 2){
    do_step(pfA, ss);
    if (ss + 1 < steps) do_step(pfB, ss + 1);
  }

  #pragma unroll
  for (int r = 0; r < 4; r++){
    int m = kg*4 + r;
    float* st = state + (((size_t)d*NSEQ + seq0 + m)*2)*192;
    st[col] = b2f(h_lds[cur][m][col]);
    st[192 + col] = c_reg[r];
  }
}

// ---------------- convT as GEMM: K-split B staging (4 phases, 36.9KB LDS -> 4 blocks/CU) ----------------
// 128 output rows/block (8 waves x 16), N=48, K=1536 (4 phases of 384 = 1 conv tap each).
template<int MODE>
__global__ __launch_bounds__(512) void gemm_convt(
    const unsigned short* __restrict__ hs, const unsigned short* __restrict__ lwt2,
    const float* __restrict__ lb, const float* __restrict__ addsrc, float* __restrict__ dst)
{
  constexpr int Q  = MODE ? 512 : 65;
  const int lane = threadIdx.x & 63, wave = threadIdx.x >> 6;   // 8 waves
  const int kg = lane >> 4, lr = lane & 15;
  const int R0 = blockIdx.x * 128;

  __shared__ union __align__(16) U {
    unsigned short b[48*48*8];   // 36,864 B : one tap's B slice
    float c[128][53];
  } sm;

  const int row = R0 + wave*16 + lr;
  const int an = row / Q, aq = row - an*Q;

  f32x4 acc[3] = {};
  #pragma unroll
  for (int p = 0; p < 4; p++){
    if (p) __syncthreads();   // prior-phase reads done before restage
    for (int cidx = threadIdx.x; cidx < 2304; cidx += 512)
      *(uint4*)&sm.b[(size_t)cidx*8] = *(const uint4*)(lwt2 + ((size_t)p*2304 + cidx)*8);
    __syncthreads();

    // phase p == tap p: rows aq+3-p
    const unsigned short* ab0 = hs + ((size_t)an*(Q+3) + aq + 3 - p)*384 + kg*8;

    bf16x8 pfA = *(const bf16x8*)(ab0);
    bf16x8 pfB = *(const bf16x8*)(ab0 + 32);
    bf16x8 pfC = *(const bf16x8*)(ab0 + 64);
    for (int kt = 0; kt < 12; kt++){
      bf16x8 a = pfA; pfA = pfB; pfB = pfC;
      int nk = kt + 3;
      if (nk < 12)
        pfC = *(const bf16x8*)(ab0 + nk*32);
      const int bo = (kt*4 + kg)*48*8;
      #pragma unroll
      for (int nt = 0; nt < 3; nt++){
        bf16x8 bfr = *(const bf16x8*)&sm.b[bo + (nt*16 + lr)*8];
        acc[nt] = __builtin_amdgcn_mfma_f32_16x16x32_bf16(a, bfr, acc[nt], 0,0,0);
      }
    }
  }

  if (MODE == 0){
    __syncthreads();
    #pragma unroll
    for (int nt = 0; nt < 3; nt++)
      #pragma unroll
      for (int r = 0; r < 4; r++)
        sm.c[wave*16 + kg*4 + r][nt*16 + lr] = acc[nt][r];
    __syncthreads();
    const int b = R0 >= 33280 ? 1 : 0;
    const size_t bb = (size_t)b*1597440;
    const int rb = R0 - b*33280;
    for (int idx = threadIdx.x; idx < 48*32; idx += 512){
      int n = idx >> 5, g = idx & 31;
      size_t off = bb + (size_t)n*33280 + rb + g*4;
      float4 av = *(const float4*)(addsrc + off);
      float lbn = lb[n];
      float4 o;
      o.x = sm.c[g*4+0][n] + lbn + av.x;
      o.y = sm.c[g*4+1][n] + lbn + av.y;
      o.z = sm.c[g*4+2][n] + lbn + av.z;
      o.w = sm.c[g*4+3][n] + lbn + av.w;
      *(float4*)(dst + off) = o;
    }
  } else {
    #pragma unroll
    for (int nt = 0; nt < 3; nt++){
      int n = nt*16 + lr;
      float lbn = lb[n];
      #pragma unroll
      for (int r = 0; r < 4; r++){
        int orow = R0 + wave*16 + kg*4 + r;
        int ns = orow >> 9, t = orow & 511;
        size_t off = (size_t)(ns/65)*1597440 + (size_t)n*33280 + (ns%65) + (size_t)t*65;
        dst[off] = acc[nt][r] + lbn + addsrc[off];
      }
    }
  }
}

// ---------------- generic row-major bf16 GEMM (BT layout), batched ----------------
__global__ __launch_bounds__(256) void gemm_rm(
    const unsigned short* __restrict__ A, const unsigned short* __restrict__ B, float* __restrict__ C,
    int lda, int ldb, int ldc, int KT, int nmax, long long strA, long long strB, long long strC)
{
  const int z = blockIdx.z;
  A += (size_t)z * strA; B += (size_t)z * strB; C += (size_t)z * strC;
  const int lane = threadIdx.x & 63, wave = threadIdx.x >> 6;
  const int kg = lane >> 4, lr = lane & 15;
  const int rowbase = blockIdx.x*128 + wave*32;
  const int nbase = blockIdx.y*64;
  f32x4 acc[2][4] = {};
  for (int kt = 0; kt < KT; kt++){
    int k0 = kt*32 + kg*8;
    bf16x8 a0 = *(const bf16x8*)(A + (size_t)(rowbase+lr)*lda + k0);
    bf16x8 a1 = *(const bf16x8*)(A + (size_t)(rowbase+16+lr)*lda + k0);
    #pragma unroll
    for (int nt = 0; nt < 4; nt++){
      bf16x8 bfr = *(const bf16x8*)(B + (size_t)(nbase+nt*16+lr)*ldb + k0);
      acc[0][nt] = __builtin_amdgcn_mfma_f32_16x16x32_bf16(a0, bfr, acc[0][nt], 0,0,0);
      acc[1][nt] = __builtin_amdgcn_mfma_f32_16x16x32_bf16(a1, bfr, acc[1][nt], 0,0,0);
    }
  }
  #pragma unroll
  for (int mt = 0; mt < 2; mt++)
  #pragma unroll
  for (int nt = 0; nt < 4; nt++)
  #pragma unroll
  for (int r = 0; r < 4; r++){
    int n = nbase + nt*16 + lr;
    if (n < nmax){
      int row = rowbase + mt*16 + kg*4 + r;
      C[(size_t)row*ldc + n] = acc[mt][nt][r];
    }
  }
}

// ---------------- FUSED qkv projection + prelu + LN over (e,f): float4 LDS, padded rows ----------------
// in_t [65][52]: pad 48->52 so bank-quad = (13f + c4) mod 8 sweeps all 8 -> conflict-free b128.
__global__ __launch_bounds__(256) void qkv3_k(
    const float* __restrict__ inter,
    const float* __restrict__ qw, const float* __restrict__ qb, const float* __restrict__ qa,
    const float* __restrict__ qg, const float* __restrict__ qbe,
    const float* __restrict__ kw, const float* __restrict__ kb, const float* __restrict__ ka,
    const float* __restrict__ kgm, const float* __restrict__ kbe,
    const float* __restrict__ vw, const float* __restrict__ vb, const float* __restrict__ va,
    const float* __restrict__ vg, const float* __restrict__ vbe,
    unsigned short* __restrict__ q2b, unsigned short* __restrict__ k2b,
    unsigned short* __restrict__ v2t)
{
  int t = blockIdx.x; int hb = blockIdx.y; int h = hb >> 1, b = hb & 1;
  __shared__ __align__(16) float in_t[65][52];
  __shared__ __align__(16) float w_l[28][48];
  __shared__ float y_l[780];
  __shared__ float rs1[4], rs2[4];
  const float* base = inter + (size_t)b*(48*512*65) + (size_t)t*65;
  for (int i = threadIdx.x; i < 48*65; i += 256){
    int c = i/65, q = i - c*65;
    in_t[q][c] = base[(size_t)c*(512*65) + q];
  }
  for (int i = threadIdx.x; i < 8*48; i += 256)  w_l[i/48][i%48]      = qw[(size_t)h*8*48 + i];
  for (int i = threadIdx.x; i < 8*48; i += 256)  w_l[8 + i/48][i%48]  = kw[(size_t)h*8*48 + i];
  for (int i = threadIdx.x; i < 12*48; i += 256) w_l[16 + i/48][i%48] = vw[(size_t)h*12*48 + i];
  __syncthreads();

  #pragma unroll
  for (int ph = 0; ph < 3; ph++){
    const int E   = (ph == 2) ? 12 : 8;
    const int wo  = (ph == 0) ? 0 : (ph == 1 ? 8 : 16);
    const float* bias  = (ph == 0) ? qb  : (ph == 1 ? kb  : vb);
    const float* alpha = (ph == 0) ? qa  : (ph == 1 ? ka  : va);
    const float* gam   = (ph == 0) ? qg  : (ph == 1 ? kgm : vg);
    const float* bet   = (ph == 0) ? qbe : (ph == 1 ? kbe : vbe);
    int nel = E*65;
    float a = alpha[h];
    float ps = 0.f, pq = 0.f;
    for (int i = threadIdx.x; i < nel; i += 256){
      int e = i/65, f = i - e*65;
      float s = bias[h*E + e];
      const float4* wr = (const float4*)&w_l[wo + e][0];
      const float4* xr = (const float4*)&in_t[f][0];
      #pragma unroll
      for (int c4 = 0; c4 < 12; c4++){
        float4 wv = wr[c4], xv = xr[c4];
        s += wv.x*xv.x + wv.y*xv.y + wv.z*xv.z + wv.w*xv.w;
      }
      s = s >= 0.f ? s : a*s;
      y_l[i] = s; ps += s; pq += s*s;
    }
    #pragma unroll
    for (int o = 32; o; o >>= 1){ ps += __shfl_xor(ps, o); pq += __shfl_xor(pq, o); }
    if ((threadIdx.x & 63) == 0){ rs1[threadIdx.x>>6] = ps; rs2[threadIdx.x>>6] = pq; }
    __syncthreads();
    ps = rs1[0]+rs1[1]+rs1[2]+rs1[3]; pq = rs2[0]+rs2[1]+rs2[2]+rs2[3];
    float inv = 1.0f/(float)nel;
    float m = ps*inv; float rstd = rsqrtf(pq*inv - m*m + 1e-5f);
    for (int i = threadIdx.x; i < nel; i += 256){
      int e = i/65, f = i - e*65;
      float v = (y_l[i]-m)*rstd*gam[(size_t)(h*E+e)*65 + f] + bet[(size_t)(h*E+e)*65 + f];
      if (ph == 0)      q2b[((size_t)hb*512 + t)*544 + i] = f2bf(v);
      else if (ph == 1) k2b[((size_t)hb*512 + t)*544 + i] = f2bf(v);
      else              v2t[((size_t)hb*832 + i)*512 + t] = f2bf(v);
    }
    __syncthreads();
  }
}

// ---------------- softmax over rows of 512 ----------------
__global__ __launch_bounds__(256) void softmax_k(const float* __restrict__ S, unsigned short* __restrict__ P){
  size_t row = (size_t)blockIdx.y*512 + blockIdx.x;
  const float* s = S + row*512;
  int tid = threadIdx.x;
  float v0 = s[tid], v1 = s[tid+256];
  float m = fmaxf(v0, v1);
  #pragma unroll
  for (int o = 32; o; o >>= 1) m = fmaxf(m, __shfl_xor(m, o));
  __shared__ float r4[4], q4[4];
  if ((tid & 63) == 0) r4[tid>>6] = m;
  __syncthreads();
  m = fmaxf(fmaxf(r4[0], r4[1]), fmaxf(r4[2], r4[3]));
  const float sc = 0.04385290096535146f;  // 1/sqrt(520)
  float e0 = __expf((v0-m)*sc), e1 = __expf((v1-m)*sc);
  float su = e0 + e1;
  #pragma unroll
  for (int o = 32; o; o >>= 1) su += __shfl_xor(su, o);
  if ((tid & 63) == 0) q4[tid>>6] = su;
  __syncthreads();
  su = q4[0]+q4[1]+q4[2]+q4[3];
  float inv = __builtin_amdgcn_rcpf(su);
  unsigned short* p = P + row*512;
  p[tid] = f2bf(e0*inv); p[tid+256] = f2bf(e1*inv);
}

// ---------------- final projection + prelu + LN over (c,f) + residual ----------------
__global__ __launch_bounds__(256) void pout_k(
    const float* __restrict__ o, const float* __restrict__ pw, const float* __restrict__ pb,
    const float* __restrict__ pa, const float* __restrict__ pg, const float* __restrict__ pbe,
    const float* __restrict__ inter, float* __restrict__ out)
{
  int bt = blockIdx.x; int b = bt >> 9, t = bt & 511;
  __shared__ float o_l[48][66];
  __shared__ float pw_l[48][48];
  __shared__ float p_l[3120];
  __shared__ float rs1[4], rs2[4];
  for (int i = threadIdx.x; i < 48*65; i += 256){
    int c = i/65, f = i - c*65; int h = c/12, dd = c - h*12;
    o_l[c][f] = o[((size_t)(h*2+b)*512 + t)*780 + dd*65 + f];
  }
  for (int i = threadIdx.x; i < 48*48; i += 256) pw_l[i/48][i - (i/48)*48] = pw[i];
  __syncthreads();
  float a = pa[0];
  float ps = 0.f, pq = 0.f;
  for (int i = threadIdx.x; i < 3120; i += 256){
    int oc = i/65, f = i - oc*65;
    float s = pb[oc];
    #pragma unroll
    for (int c = 0; c < 48; c++) s += pw_l[oc][c]*o_l[c][f];
    s = s >= 0.f ? s : a*s;
    p_l[i] = s; ps += s; pq += s*s;
  }
  #pragma unroll
  for (int o2 = 32; o2; o2 >>= 1){ ps += __shfl_xor(ps, o2); pq += __shfl_xor(pq, o2); }
  if ((threadIdx.x & 63) == 0){ rs1[threadIdx.x>>6] = ps; rs2[threadIdx.x>>6] = pq; }
  __syncthreads();
  ps = rs1[0]+rs1[1]+rs1[2]+rs1[3]; pq = rs2[0]+rs2[1]+rs2[2]+rs2[3];
  float m = ps*(1.0f/3120.0f); float rstd = rsqrtf(pq*(1.0f/3120.0f) - m*m + 1e-5f);
  for (int i = threadIdx.x; i < 3120; i += 256){
    int oc = i/65, f = i - oc*65;
    size_t off = ((size_t)(b*48+oc)*512 + t)*65 + f;
    out[off] = (p_l[i]-m)*rstd*pg[i] + pbe[i] + inter[off];
  }
}

// ---------------- launch ----------------

extern "C" void kernel_launch(void* const* d_in, const int* in_sizes, int n_in,
                              void* d_out, int out_size, void* d_ws, size_t ws_size,
                              hipStream_t stream)
{
  const float* x         = (const float*)d_in[0];
  const float* intra_g   = (const float*)d_in[2];
  const float* intra_b   = (const float*)d_in[3];
  const float* intra_wih = (const float*)d_in[4];
  const float* intra_whh = (const float*)d_in[5];
  const float* intra_bih = (const float*)d_in[6];
  const float* intra_bhh = (const float*)d_in[7];
  const float* intra_lw  = (const float*)d_in[8];
  const float* intra_lb  = (const float*)d_in[9];
  const float* inter_g   = (const float*)d_in[10];
  const float* inter_b   = (const float*)d_in[11];
  const float* inter_wih = (const float*)d_in[12];
  const float* inter_whh = (const float*)d_in[13];
  const float* inter_bih = (const float*)d_in[14];
  const float* inter_bhh = (const float*)d_in[15];
  const float* inter_lw  = (const float*)d_in[16];
  const float* inter_lb  = (const float*)d_in[17];
  const float* qw  = (const float*)d_in[18];
  const float* qb  = (const float*)d_in[19];
  const float* qa  = (const float*)d_in[20];
  const float* qg  = (const float*)d_in[21];
  const float* qbe = (const float*)d_in[22];
  const float* kw  = (const float*)d_in[23];
  const float* kb  = (const float*)d_in[24];
  const float* ka  = (const float*)d_in[25];
  const float* kgm = (const float*)d_in[26];
  const float* kbe = (const float*)d_in[27];
  const float* vw  = (const float*)d_in[28];
  const float* vb  = (const float*)d_in[29];
  const float* va  = (const float*)d_in[30];
  const float* vg  = (const float*)d_in[31];
  const float* vbe = (const float*)d_in[32];
  const float* pw  = (const float*)d_in[33];
  const float* pb  = (const float*)d_in[34];
  const float* pa  = (const float*)d_in[35];
  const float* pgm = (const float*)d_in[36];
  const float* pbe = (const float*)d_in[37];

  char* ws = (char*)d_ws;
  constexpr size_t WIB_INTRA = 0;
  constexpr size_t WHB_INTRA = 589824;
  constexpr size_t WIB_INTER = 1179648;
  constexpr size_t WHB_INTER = 1769472;
  constexpr size_t LWT_INTRA = 2359296;
  constexpr size_t LWT_INTER = 2555904;
  constexpr size_t BIAS_INTRA = 2752512;
  constexpr size_t BIAS_INTER = 2758656;
  constexpr size_t UNF   = 2764800;
  constexpr size_t INTER = 2764800;            // alias: written only after UNF is dead
  constexpr size_t STATE = 28311552;
  constexpr size_t HS    = 31457280;
  constexpr size_t INTRA = 84934656;
  constexpr size_t XG    = 97714176;           // double-buffered region (50,331,648 B)
  constexpr size_t Q2B   = XG;
  constexpr size_t K2B   = XG + 4456448;
  constexpr size_t V2T   = XG + 8912896;
  constexpr size_t SCORES= XG + 15728640;
  constexpr size_t ATTNB = XG + 24117248;
  constexpr size_t OBUF  = XG + 28311552;

  auto U16 = [&](size_t off){ return (unsigned short*)(ws + off); };
  auto F32 = [&](size_t off){ return (float*)(ws + off); };

  // ---- prep (single dispatch) ----
  prep_all<<<5197,256,0,stream>>>(intra_wih, intra_whh, inter_wih, inter_whh,
                                  intra_bih, intra_bhh, inter_bih, inter_bhh,
                                  intra_lw, inter_lw,
                                  U16(WIB_INTRA), U16(WHB_INTRA), U16(WIB_INTER), U16(WHB_INTER),
                                  F32(BIAS_INTRA), F32(BIAS_INTER),
                                  U16(LWT_INTRA), U16(LWT_INTER));

  // ---- intra stage (TW=8, 8 windows, xg fused with rec) ----
  {
    unsigned short* xb[2] = { U16(XG), U16(XG + 25165824) };
    ln_unf_intra<<<1024,256,0,stream>>>(x, intra_g, intra_b, U16(UNF));
    zero_stage<<<9984,256,0,stream>>>(U16(HS), 1024, 68, 62, (uint4*)(ws+STATE));
    gemm_xg<<<dim3(64,12,2),256,0,stream>>>(U16(UNF), U16(WIB_INTRA), F32(BIAS_INTRA), xb[0],
                                            1024, 8, 0, 62, 1024);
    for (int w = 0; w < 8; w++){
      int win0 = w*8;
      int steps = (62 - win0) < 8 ? (62 - win0) : 8;
      int nxg = (w < 7) ? 1536 : 0;   // 2 dirs x 64 sb x 1 slb x 12 nb
      fused_rec_xg<<<128 + nxg, 768, 0, stream>>>(
          xb[w&1], U16(WHB_INTRA), U16(HS), F32(STATE),
          U16(UNF), U16(WIB_INTRA), F32(BIAS_INTRA), xb[(w+1)&1],
          1024, 8, win0, 62, 68, 1024, steps,
          128, 64, 1, (w+1)*8);
    }
    gemm_convt<0><<<520,512,0,stream>>>(U16(HS), U16(LWT_INTRA), intra_lb, x, F32(INTRA));
  }

  // ---- inter stage (TW=48, 11 windows, xg fused with rec) ----
  {
    unsigned short* xb[2] = { U16(XG), U16(XG + 21233664) };
    ln_unf_inter<<<1024,256,0,stream>>>(F32(INTRA), inter_g, inter_b, U16(UNF));
    zero_stage<<<1938,256,0,stream>>>(U16(HS), 130, 515, 509, (uint4*)(ws+STATE));
    gemm_xg<<<dim3(54,12,2),256,0,stream>>>(U16(UNF), U16(WIB_INTER), F32(BIAS_INTER), xb[0],
                                            144, 48, 0, 509, 130);
    for (int w = 0; w < 11; w++){
      int win0 = w*48;
      int steps = (509 - win0) < 48 ? (509 - win0) : 48;
      int nxg = (w < 10) ? 864 : 0;   // 2 dirs x 9 sb x 4 slb x 12 nb
      fused_rec_xg<<<18 + nxg, 768, 0, stream>>>(
          xb[w&1], U16(WHB_INTER), U16(HS), F32(STATE),
          U16(UNF), U16(WIB_INTER), F32(BIAS_INTER), xb[(w+1)&1],
          144, 48, win0, 509, 515, 130, steps,
          18, 9, 4, (w+1)*48);
    }
    gemm_convt<1><<<520,512,0,stream>>>(U16(HS), U16(LWT_INTER), inter_lb, F32(INTRA), F32(INTER));
  }

  // ---- attention stage ----
  zero16<<<2048,256,0,stream>>>((uint4*)(ws+Q2B), 15728640/16);
  qkv3_k<<<dim3(512,8),256,0,stream>>>(F32(INTER),
                                       qw, qb, qa, qg, qbe,
                                       kw, kb, ka, kgm, kbe,
                                       vw, vb, va, vg, vbe,
                                       U16(Q2B), U16(K2B), U16(V2T));
  gemm_rm<<<dim3(4,8,8),256,0,stream>>>(U16(Q2B), U16(K2B), F32(SCORES),
                                        544, 544, 512, 17, 512,
                                        (long long)512*544, (long long)512*544, (long long)512*512);
  softmax_k<<<dim3(512,8),256,0,stream>>>(F32(SCORES), U16(ATTNB));
  gemm_rm<<<dim3(4,13,8),256,0,stream>>>(U16(ATTNB), U16(V2T), F32(OBUF),
                                         512, 512, 780, 16, 780,
                                         (long long)512*512, (long long)832*512, (long long)512*780);
  pout_k<<<1024,256,0,stream>>>(F32(OBUF), pw, pb, pa, pgm, pbe, F32(INTER), (float*)d_out);
}